// Round 4
// baseline (426.440 us; speedup 1.0000x reference)
//
#include <hip/hip_runtime.h>
#include <hip/hip_bf16.h>
#include <math.h>

#define M_HALF 2097152          // 2^21, half-length complex IFFT size
#define NQ     262144           // M_HALF / 8, threads per FFT pass

typedef __bf16 bf16_t;
typedef __attribute__((ext_vector_type(8))) __bf16 bf8;
typedef __attribute__((ext_vector_type(4))) __bf16 bf4;
typedef __attribute__((ext_vector_type(4))) float f32x4;

#define GLOBAL_AS __attribute__((address_space(1)))
#define LDS_AS    __attribute__((address_space(3)))

__device__ __forceinline__ float2 cadd(float2 a, float2 b){ return make_float2(a.x+b.x, a.y+b.y); }
__device__ __forceinline__ float2 csub(float2 a, float2 b){ return make_float2(a.x-b.x, a.y-b.y); }
__device__ __forceinline__ float2 cmul(float2 a, float2 b){ return make_float2(a.x*b.x-a.y*b.y, a.x*b.y+a.y*b.x); }
__device__ __forceinline__ float2 cmuli(float2 a){ return make_float2(-a.y, a.x); } // *(+i)

// ---------------- zero / scatter / preprocess ----------------

__global__ __launch_bounds__(256) void zero2_kernel(float2* p, int n) {
    int i = blockIdx.x*256 + threadIdx.x;
    if (i < n) p[i] = make_float2(0.f, 0.f);
}

__global__ __launch_bounds__(256) void scatter_kernel(const float* __restrict__ cr,
                                                      const float* __restrict__ ci,
                                                      const int* __restrict__ idx,
                                                      float2* __restrict__ spec, int keep) {
    int i = blockIdx.x*256 + threadIdx.x;
    if (i < keep) {
        int k = idx[i];
        spec[k] = make_float2(cr[i], ci[i]);
    }
}

__global__ __launch_bounds__(256) void prep_kernel(const float2* __restrict__ spec,
                                                   float2* __restrict__ Z,
                                                   const float* __restrict__ scale) {
    int k = blockIdx.x*256 + threadIdx.x;
    float2 a = spec[k];
    float2 b = spec[M_HALF - k];
    if (k == 0) { a.y = 0.0f; b.y = 0.0f; }   // c2r ignores imag of DC & Nyquist
    float Er = 0.5f*(a.x + b.x), Ei = 0.5f*(a.y - b.y);
    float Tr = 0.5f*(a.x - b.x), Ti = 0.5f*(a.y + b.y);
    float ang = (float)(3.14159265358979323846 * (double)k / (double)M_HALF);
    float sn, cs; sincosf(ang, &sn, &cs);
    float Or = Tr*cs - Ti*sn;
    float Oi = Tr*sn + Ti*cs;
    float s = scale[0] * (1.0f/(float)M_HALF);
    Z[k] = make_float2((Er - Oi)*s, (Ei + Or)*s);
}

// ---------------- radix-8 Stockham inverse FFT pass ----------------
template<int NS>
__global__ __launch_bounds__(256) void ifft_pass8(const float2* __restrict__ src,
                                                  float2* __restrict__ dst) {
    int j = blockIdx.x*256 + threadIdx.x;   // j < NQ
    float2 v[8];
#pragma unroll
    for (int t = 0; t < 8; ++t) v[t] = src[j + t*NQ];
    int jm = j & (NS - 1);
    if constexpr (NS > 1) {
        double base = (double)jm / (double)(NS * 8);
#pragma unroll
        for (int t = 1; t < 8; ++t) {
            float ang = (float)(6.283185307179586 * base * (double)t);
            float sn, cs; sincosf(ang, &sn, &cs);
            v[t] = cmul(v[t], make_float2(cs, sn));
        }
    }
    const float cc = 0.70710678118654752f;
    float2 a0 = cadd(v[0], v[4]), a1 = cadd(v[1], v[5]), a2 = cadd(v[2], v[6]), a3 = cadd(v[3], v[7]);
    float2 b0 = csub(v[0], v[4]), b1 = csub(v[1], v[5]), b2 = csub(v[2], v[6]), b3 = csub(v[3], v[7]);
    b1 = cmul(b1, make_float2(cc, cc));
    b2 = cmuli(b2);
    b3 = cmul(b3, make_float2(-cc, cc));
    float2 c0 = cadd(a0, a2), c1 = cadd(a1, a3), d0 = csub(a0, a2), d1 = cmuli(csub(a1, a3));
    float2 e0 = cadd(b0, b2), e1 = cadd(b1, b3), f0 = csub(b0, b2), f1 = cmuli(csub(b1, b3));
    float2 X0 = cadd(c0, c1), X4 = csub(c0, c1), X2 = cadd(d0, d1), X6 = csub(d0, d1);
    float2 X1 = cadd(e0, e1), X5 = csub(e0, e1), X3 = cadd(f0, f1), X7 = csub(f0, f1);
    int idxD = ((j - jm) << 3) + jm;
    dst[idxD + 0*NS] = X0;
    dst[idxD + 1*NS] = X1;
    dst[idxD + 2*NS] = X2;
    dst[idxD + 3*NS] = X3;
    dst[idxD + 4*NS] = X4;
    dst[idxD + 5*NS] = X5;
    dst[idxD + 6*NS] = X6;
    dst[idxD + 7*NS] = X7;
}

// ---------------- transpose fp32 -> bf16 (w[R][C] -> wT[C][R]) ----------------

__global__ __launch_bounds__(256) void transpose_kernel(const float* __restrict__ w,
                                                        bf16_t* __restrict__ wT,
                                                        int R, int C) {
    __shared__ float tile[32][33];
    int tx = threadIdx.x & 31, ty = threadIdx.x >> 5;
    long c0 = (long)blockIdx.x * 32, r0 = (long)blockIdx.y * 32;
#pragma unroll
    for (int i = 0; i < 4; ++i)
        tile[ty + i*8][tx] = w[(r0 + ty + i*8) * C + c0 + tx];
    __syncthreads();
#pragma unroll
    for (int i = 0; i < 4; ++i) {
        int c = ty + i*8;
        wT[(c0 + c) * R + r0 + tx] = (bf16_t)tile[tx][c];
    }
}

// ---------------- fp32 -> bf16 convert (x) ----------------

__global__ __launch_bounds__(256) void cvt_bf16_kernel(const float* __restrict__ in,
                                                       bf16_t* __restrict__ out, int n4) {
    int i = blockIdx.x*256 + threadIdx.x;
    if (i < n4) {
        float4 v = ((const float4*)in)[i];
        bf4 o;
        o[0] = (bf16_t)v.x; o[1] = (bf16_t)v.y; o[2] = (bf16_t)v.z; o[3] = (bf16_t)v.w;
        ((bf4*)out)[i] = o;
    }
}

// ---------------- 128-tile MFMA GEMM (kept for GEMM2) ----------------

__device__ __forceinline__ void stage_tile(const bf16_t* g, int ld, int row0, int col0,
                                           bf16_t* lds, int tid) {
    int w = tid >> 6, l = tid & 63;
#pragma unroll
    for (int i = 0; i < 4; ++i) {
        int chunk = (i << 2) + w;
        int e = (chunk << 9) + (l << 3);
        int r = e >> 6, c = e & 63;
        const bf16_t* ga = g + (long)(row0 + r) * ld + col0 + c;
        bf16_t* la = lds + (chunk << 9);
        __builtin_amdgcn_global_load_lds((const GLOBAL_AS unsigned int*)ga,
                                         (LDS_AS unsigned int*)la, 16, 0, 0);
    }
}

template<int EPI>  // 0: bias+gelu -> bf16 ; 1: bias -> fp32
__global__ __launch_bounds__(256) void gemm_bt(const bf16_t* __restrict__ A,
                                               const bf16_t* __restrict__ Bt,
                                               const float* __restrict__ bias,
                                               void* __restrict__ Cout,
                                               int M, int N, int K) {
    __shared__ __align__(16) bf16_t lA[128*64];
    __shared__ __align__(16) bf16_t lB[128*64];
    const int tid = threadIdx.x;
    const int l = tid & 63, w = tid >> 6;
    const int wr = w >> 1, wc = w & 1;
    const int row0 = blockIdx.y * 128, col0 = blockIdx.x * 128;
    f32x4 acc[4][4] = {};
    for (int k0 = 0; k0 < K; k0 += 64) {
        stage_tile(A,  K, row0, k0, lA, tid);
        stage_tile(Bt, K, col0, k0, lB, tid);
        __syncthreads();
#pragma unroll
        for (int kk = 0; kk < 64; kk += 32) {
            bf8 af[4], bfr[4];
            const int lr = l & 15, lk = kk + ((l >> 4) << 3);
#pragma unroll
            for (int mi = 0; mi < 4; ++mi)
                af[mi] = *(const bf8*)&lA[(wr*64 + mi*16 + lr)*64 + lk];
#pragma unroll
            for (int ni = 0; ni < 4; ++ni)
                bfr[ni] = *(const bf8*)&lB[(wc*64 + ni*16 + lr)*64 + lk];
#pragma unroll
            for (int mi = 0; mi < 4; ++mi)
#pragma unroll
                for (int ni = 0; ni < 4; ++ni)
                    acc[mi][ni] = __builtin_amdgcn_mfma_f32_16x16x32_bf16(
                        af[mi], bfr[ni], acc[mi][ni], 0, 0, 0);
        }
        __syncthreads();
    }
    const int fr = l & 15, fq = l >> 4;
#pragma unroll
    for (int mi = 0; mi < 4; ++mi) {
#pragma unroll
        for (int ni = 0; ni < 4; ++ni) {
#pragma unroll
            for (int q = 0; q < 4; ++q) {
                int r = row0 + wr*64 + mi*16 + fq*4 + q;
                int c = col0 + wc*64 + ni*16 + fr;
                float v = acc[mi][ni][q] + bias[c];
                if constexpr (EPI == 0) {
                    v = 0.5f * v * (1.0f + erff(v * 0.70710678118654752f));
                    ((bf16_t*)Cout)[(long)r * N + c] = (bf16_t)v;
                } else {
                    ((float*)Cout)[(long)r * N + c] = v;
                }
            }
        }
    }
}

// ---------------- 256x256 MFMA GEMM, 4-window schedule ----------------
// Round-4: removed ALL sched_barrier(0) + blanket lgkmcnt(0) (m141 poison);
// reads issued one window ahead of use so the compiler's fine-grained
// lgkmcnt(N) waits let ds_reads drain under MFMA clusters. Barriers 8->4/tile.
// Staging of tile t+1 batched at W0; per-wave vmcnt(0) before tile-end barrier
// fences staging vs next tile's reads.

__device__ __forceinline__ void stage_half(const bf16_t* __restrict__ g, int ldK,
                                           long grow0, int k0, char* lds,
                                           int wid, int lane) {
    int r8 = lane >> 3;                       // row within 8-row chunk
    int cg = ((lane & 7) ^ r8) << 3;          // pre-swizzled element col (0..56)
#pragma unroll
    for (int j = 0; j < 2; ++j) {
        int chunk = j*8 + wid;                // 16 x 1KiB chunks per half-tile
        const bf16_t* ga = g + (grow0 + chunk*8 + r8) * (long)ldK + (k0 + cg);
        __builtin_amdgcn_global_load_lds((const GLOBAL_AS unsigned int*)ga,
                                         (LDS_AS unsigned int*)(lds + chunk*1024),
                                         16, 0, 0);
    }
}

template<int EPI>
__global__ __launch_bounds__(512, 2) void gemm256(const bf16_t* __restrict__ A,
                                                  const bf16_t* __restrict__ Bt,
                                                  const float* __restrict__ bias,
                                                  void* __restrict__ Cout,
                                                  int M, int N, int K, int TN) {
    __shared__ __align__(16) char smem[131072];
    const int tid = threadIdx.x;
    const int lane = tid & 63, wid = tid >> 6;
    const int wr = wid >> 2, wc = wid & 3;
    const int lr = lane & 15, lq = lane >> 4;

    // bijective XCD swizzle (grid is a multiple of 8)
    int cpx = gridDim.x >> 3;
    int bid = blockIdx.x;
    int swz = (bid & 7) * cpx + (bid >> 3);
    const long row0 = (long)(swz / TN) * 256;
    const long col0 = (long)(swz % TN) * 256;
    const int NT = K >> 6;

    // per-lane swizzled frag offsets (byte, within a 16 KiB half-tile)
    const int xr  = (lr & 7) << 4;
    const int kA0 = lr*128 + ((lq*16) ^ xr);          // kk=0
    const int kA1 = lr*128 + ((64 + lq*16) ^ xr);     // kk=32

    bf8 aL[4][2], aH[4][2], bL[2][2], bH[2][2];
    f32x4 acc[8][4] = {};

#define LD8(X) (*(const bf8*)(smem + (X)))

    // prologue: tile0 all 4 halves
    stage_half(A,  K, row0,       0, smem + 0,     wid, lane);
    stage_half(A,  K, row0 + 128, 0, smem + 16384, wid, lane);
    stage_half(Bt, K, col0,       0, smem + 32768, wid, lane);
    stage_half(Bt, K, col0 + 128, 0, smem + 49152, wid, lane);
    asm volatile("s_waitcnt vmcnt(0)" ::: "memory");
    __builtin_amdgcn_s_barrier();

    for (int t = 0; t < NT; ++t) {
        const int bufb = (t & 1) << 16;
        const int nbuf = ((t + 1) & 1) << 16;
        const int ao = bufb + (wr << 14);
        const int bo = bufb + 32768 + ((wc >> 1) << 14) + ((wc & 1) << 13);

        // ---- W0: stage ALL of tile t+1 ; read aL (P0), bL+bH (P0..P3) ----
        if (t + 1 < NT) {
            const int nk = (t + 1) << 6;
            stage_half(A,  K, row0,       nk, smem + nbuf,         wid, lane);
            stage_half(A,  K, row0 + 128, nk, smem + nbuf + 16384, wid, lane);
            stage_half(Bt, K, col0,       nk, smem + nbuf + 32768, wid, lane);
            stage_half(Bt, K, col0 + 128, nk, smem + nbuf + 49152, wid, lane);
        }
#pragma unroll
        for (int mi = 0; mi < 4; ++mi) {
            aL[mi][0] = LD8(ao + kA0 + mi*2048);
            aL[mi][1] = LD8(ao + kA1 + mi*2048);
        }
#pragma unroll
        for (int ni = 0; ni < 2; ++ni) {
            bL[ni][0] = LD8(bo + kA0 + ni*2048);
            bL[ni][1] = LD8(bo + kA1 + ni*2048);
            bH[ni][0] = LD8(bo + kA0 + (ni+2)*2048);
            bH[ni][1] = LD8(bo + kA1 + (ni+2)*2048);
        }
        __builtin_amdgcn_s_barrier();

        // ---- P0: mi0-3 x ni0-1 ----
        __builtin_amdgcn_s_setprio(1);
#pragma unroll
        for (int mi = 0; mi < 4; ++mi)
#pragma unroll
            for (int ni = 0; ni < 2; ++ni)
#pragma unroll
                for (int k = 0; k < 2; ++k)
                    acc[mi][ni] = __builtin_amdgcn_mfma_f32_16x16x32_bf16(
                        aL[mi][k], bL[ni][k], acc[mi][ni], 0, 0, 0);
        __builtin_amdgcn_s_setprio(0);
        __builtin_amdgcn_s_barrier();

        // ---- W1: read aH (P2/P3 operands) ----
#pragma unroll
        for (int mi = 0; mi < 4; ++mi) {
            aH[mi][0] = LD8(ao + kA0 + (mi+4)*2048);
            aH[mi][1] = LD8(ao + kA1 + (mi+4)*2048);
        }
        __builtin_amdgcn_s_barrier();

        // ---- P1 + P2 + P3 (aH reads drain under P1) ----
        __builtin_amdgcn_s_setprio(1);
#pragma unroll
        for (int mi = 0; mi < 4; ++mi)
#pragma unroll
            for (int ni = 0; ni < 2; ++ni)
#pragma unroll
                for (int k = 0; k < 2; ++k)
                    acc[mi][2+ni] = __builtin_amdgcn_mfma_f32_16x16x32_bf16(
                        aL[mi][k], bH[ni][k], acc[mi][2+ni], 0, 0, 0);
#pragma unroll
        for (int mi = 0; mi < 4; ++mi)
#pragma unroll
            for (int ni = 0; ni < 2; ++ni)
#pragma unroll
                for (int k = 0; k < 2; ++k)
                    acc[4+mi][2+ni] = __builtin_amdgcn_mfma_f32_16x16x32_bf16(
                        aH[mi][k], bH[ni][k], acc[4+mi][2+ni], 0, 0, 0);
#pragma unroll
        for (int mi = 0; mi < 4; ++mi)
#pragma unroll
            for (int ni = 0; ni < 2; ++ni)
#pragma unroll
                for (int k = 0; k < 2; ++k)
                    acc[4+mi][ni] = __builtin_amdgcn_mfma_f32_16x16x32_bf16(
                        aH[mi][k], bL[ni][k], acc[4+mi][ni], 0, 0, 0);
        __builtin_amdgcn_s_setprio(0);
        // fence: all staging done before any wave reads nbuf next tile
        asm volatile("s_waitcnt vmcnt(0)" ::: "memory");
        __builtin_amdgcn_s_barrier();
    }
#undef LD8

    // ---- epilogue ----
#pragma unroll
    for (int mi = 0; mi < 8; ++mi) {
#pragma unroll
        for (int ni = 0; ni < 4; ++ni) {
            long c = col0 + wc*64 + ni*16 + lr;
            float bv = bias[c];
#pragma unroll
            for (int q = 0; q < 4; ++q) {
                long r = row0 + wr*128 + mi*16 + lq*4 + q;
                float v = acc[mi][ni][q] + bv;
                if constexpr (EPI == 0) {
                    v = 0.5f * v * (1.0f + erff(v * 0.70710678118654752f));
                    ((bf16_t*)Cout)[r * N + c] = (bf16_t)v;
                } else {
                    ((float*)Cout)[r * N + c] = v;
                }
            }
        }
    }
}

// ---------------- launch ----------------

extern "C" void kernel_launch(void* const* d_in, const int* in_sizes, int n_in,
                              void* d_out, int out_size, void* d_ws, size_t ws_size,
                              hipStream_t stream) {
    const float* x        = (const float*)d_in[0];
    const float* fc_cr    = (const float*)d_in[1];
    const float* fc_ci    = (const float*)d_in[2];
    const int*   fc_idx   = (const int*)  d_in[3];
    const float* fc_scale = (const float*)d_in[4];
    const float* fc_bias  = (const float*)d_in[5];
    const float* pj_cr    = (const float*)d_in[6];
    const float* pj_ci    = (const float*)d_in[7];
    const int*   pj_idx   = (const int*)  d_in[8];
    const float* pj_scale = (const float*)d_in[9];
    const float* pj_bias  = (const float*)d_in[10];
    const int keep = in_sizes[1];

    char* ws = (char*)d_ws;
    bf16_t* w_fcT = (bf16_t*)(ws + 0);          //  8 MiB  [4096][1024]
    bf16_t* w_pjT = (bf16_t*)(ws + 8388608);    //  8 MiB  [1024][4096]
    bf16_t* x_bf  = (bf16_t*)(ws + 16777216);   // 16 MiB  [8192][1024]
    bf16_t* h_bf  = (bf16_t*)(ws + 33554432);   // 64 MiB  [8192][4096]
    float2* spec  = (float2*)(ws + 33554432);   // FFT scratch aliases h region
    float2* fftA  = (float2*)(ws + 50331904);
    float2* fftB  = (float2*)(ws + 67109120);

    auto run_decompress = [&](const float* cr, const float* ci, const int* idx,
                              const float* scale, bf16_t* wT, int R, int C) {
        zero2_kernel<<<(M_HALF + 1 + 255)/256, 256, 0, stream>>>(spec, M_HALF + 1);
        scatter_kernel<<<(keep + 255)/256, 256, 0, stream>>>(cr, ci, idx, spec, keep);
        prep_kernel<<<M_HALF/256, 256, 0, stream>>>(spec, fftA, scale);
        ifft_pass8<1>     <<<NQ/256, 256, 0, stream>>>(fftA, fftB);
        ifft_pass8<8>     <<<NQ/256, 256, 0, stream>>>(fftB, fftA);
        ifft_pass8<64>    <<<NQ/256, 256, 0, stream>>>(fftA, fftB);
        ifft_pass8<512>   <<<NQ/256, 256, 0, stream>>>(fftB, fftA);
        ifft_pass8<4096>  <<<NQ/256, 256, 0, stream>>>(fftA, fftB);
        ifft_pass8<32768> <<<NQ/256, 256, 0, stream>>>(fftB, fftA);
        ifft_pass8<262144><<<NQ/256, 256, 0, stream>>>(fftA, fftB);
        dim3 tg(C/32, R/32);
        transpose_kernel<<<tg, 256, 0, stream>>>((const float*)fftB, wT, R, C);
    };

    run_decompress(fc_cr, fc_ci, fc_idx, fc_scale, w_fcT, 1024, 4096);
    run_decompress(pj_cr, pj_ci, pj_idx, pj_scale, w_pjT, 4096, 1024);

    cvt_bf16_kernel<<<8388608/4/256, 256, 0, stream>>>(x, x_bf, 8388608/4);

    // GEMM1: 256^2 kernel. grid = (8192/256)*(4096/256) = 32*16 = 512
    gemm256<0><<<dim3(512), dim3(512), 0, stream>>>(
        x_bf, w_fcT, fc_bias, h_bf, 8192, 4096, 1024, 16);

    // GEMM2: keep 128^2 kernel (grid 8x64)
    gemm_bt<1><<<dim3(1024/128, 8192/128), 256, 0, stream>>>(
        h_bf, w_pjT, pj_bias, d_out, 8192, 1024, 4096);

    (void)n_in; (void)out_size; (void)ws_size;
}

// Round 5
// 417.040 us; speedup vs baseline: 1.0225x; 1.0225x over previous
//
#include <hip/hip_runtime.h>
#include <hip/hip_bf16.h>
#include <math.h>

#define M_HALF 2097152          // 2^21, half-length complex IFFT size
#define NQ     262144           // M_HALF / 8, threads per FFT pass

typedef __bf16 bf16_t;
typedef __attribute__((ext_vector_type(8))) __bf16 bf8;
typedef __attribute__((ext_vector_type(4))) __bf16 bf4;
typedef __attribute__((ext_vector_type(4))) float f32x4;

#define GLOBAL_AS __attribute__((address_space(1)))
#define LDS_AS    __attribute__((address_space(3)))

__device__ __forceinline__ float2 cadd(float2 a, float2 b){ return make_float2(a.x+b.x, a.y+b.y); }
__device__ __forceinline__ float2 csub(float2 a, float2 b){ return make_float2(a.x-b.x, a.y-b.y); }
__device__ __forceinline__ float2 cmul(float2 a, float2 b){ return make_float2(a.x*b.x-a.y*b.y, a.x*b.y+a.y*b.x); }
__device__ __forceinline__ float2 cmuli(float2 a){ return make_float2(-a.y, a.x); } // *(+i)

// ---------------- zero / scatter / preprocess ----------------

__global__ __launch_bounds__(256) void zero2_kernel(float2* p, int n) {
    int i = blockIdx.x*256 + threadIdx.x;
    if (i < n) p[i] = make_float2(0.f, 0.f);
}

__global__ __launch_bounds__(256) void scatter_kernel(const float* __restrict__ cr,
                                                      const float* __restrict__ ci,
                                                      const int* __restrict__ idx,
                                                      float2* __restrict__ spec, int keep) {
    int i = blockIdx.x*256 + threadIdx.x;
    if (i < keep) {
        int k = idx[i];
        spec[k] = make_float2(cr[i], ci[i]);
    }
}

__global__ __launch_bounds__(256) void prep_kernel(const float2* __restrict__ spec,
                                                   float2* __restrict__ Z,
                                                   const float* __restrict__ scale) {
    int k = blockIdx.x*256 + threadIdx.x;
    float2 a = spec[k];
    float2 b = spec[M_HALF - k];
    if (k == 0) { a.y = 0.0f; b.y = 0.0f; }   // c2r ignores imag of DC & Nyquist
    float Er = 0.5f*(a.x + b.x), Ei = 0.5f*(a.y - b.y);
    float Tr = 0.5f*(a.x - b.x), Ti = 0.5f*(a.y + b.y);
    float ang = (float)(3.14159265358979323846 * (double)k / (double)M_HALF);
    float sn, cs; sincosf(ang, &sn, &cs);
    float Or = Tr*cs - Ti*sn;
    float Oi = Tr*sn + Ti*cs;
    float s = scale[0] * (1.0f/(float)M_HALF);
    Z[k] = make_float2((Er - Oi)*s, (Ei + Or)*s);
}

// ---------------- radix-8 Stockham inverse FFT pass ----------------
template<int NS>
__global__ __launch_bounds__(256) void ifft_pass8(const float2* __restrict__ src,
                                                  float2* __restrict__ dst) {
    int j = blockIdx.x*256 + threadIdx.x;   // j < NQ
    float2 v[8];
#pragma unroll
    for (int t = 0; t < 8; ++t) v[t] = src[j + t*NQ];
    int jm = j & (NS - 1);
    if constexpr (NS > 1) {
        double base = (double)jm / (double)(NS * 8);
#pragma unroll
        for (int t = 1; t < 8; ++t) {
            float ang = (float)(6.283185307179586 * base * (double)t);
            float sn, cs; sincosf(ang, &sn, &cs);
            v[t] = cmul(v[t], make_float2(cs, sn));
        }
    }
    const float cc = 0.70710678118654752f;
    float2 a0 = cadd(v[0], v[4]), a1 = cadd(v[1], v[5]), a2 = cadd(v[2], v[6]), a3 = cadd(v[3], v[7]);
    float2 b0 = csub(v[0], v[4]), b1 = csub(v[1], v[5]), b2 = csub(v[2], v[6]), b3 = csub(v[3], v[7]);
    b1 = cmul(b1, make_float2(cc, cc));
    b2 = cmuli(b2);
    b3 = cmul(b3, make_float2(-cc, cc));
    float2 c0 = cadd(a0, a2), c1 = cadd(a1, a3), d0 = csub(a0, a2), d1 = cmuli(csub(a1, a3));
    float2 e0 = cadd(b0, b2), e1 = cadd(b1, b3), f0 = csub(b0, b2), f1 = cmuli(csub(b1, b3));
    float2 X0 = cadd(c0, c1), X4 = csub(c0, c1), X2 = cadd(d0, d1), X6 = csub(d0, d1);
    float2 X1 = cadd(e0, e1), X5 = csub(e0, e1), X3 = cadd(f0, f1), X7 = csub(f0, f1);
    int idxD = ((j - jm) << 3) + jm;
    dst[idxD + 0*NS] = X0;
    dst[idxD + 1*NS] = X1;
    dst[idxD + 2*NS] = X2;
    dst[idxD + 3*NS] = X3;
    dst[idxD + 4*NS] = X4;
    dst[idxD + 5*NS] = X5;
    dst[idxD + 6*NS] = X6;
    dst[idxD + 7*NS] = X7;
}

// ---------------- transpose fp32 -> bf16 (w[R][C] -> wT[C][R]) ----------------

__global__ __launch_bounds__(256) void transpose_kernel(const float* __restrict__ w,
                                                        bf16_t* __restrict__ wT,
                                                        int R, int C) {
    __shared__ float tile[32][33];
    int tx = threadIdx.x & 31, ty = threadIdx.x >> 5;
    long c0 = (long)blockIdx.x * 32, r0 = (long)blockIdx.y * 32;
#pragma unroll
    for (int i = 0; i < 4; ++i)
        tile[ty + i*8][tx] = w[(r0 + ty + i*8) * C + c0 + tx];
    __syncthreads();
#pragma unroll
    for (int i = 0; i < 4; ++i) {
        int c = ty + i*8;
        wT[(c0 + c) * R + r0 + tx] = (bf16_t)tile[tx][c];
    }
}

// ---------------- fp32 -> bf16 convert (x) ----------------

__global__ __launch_bounds__(256) void cvt_bf16_kernel(const float* __restrict__ in,
                                                       bf16_t* __restrict__ out, int n4) {
    int i = blockIdx.x*256 + threadIdx.x;
    if (i < n4) {
        float4 v = ((const float4*)in)[i];
        bf4 o;
        o[0] = (bf16_t)v.x; o[1] = (bf16_t)v.y; o[2] = (bf16_t)v.z; o[3] = (bf16_t)v.w;
        ((bf4*)out)[i] = o;
    }
}

// ---------------- 128-tile MFMA GEMM (GEMM2) ----------------
// Round-5: __launch_bounds__(256,3) — m97's operating point (~164 VGPR,
// 3 waves/SIMD). The previous bare (256) let the occupancy heuristic squeeze
// to 88 VGPR, forcing operand traffic through AGPRs (VALU moves per MFMA).

__device__ __forceinline__ void stage_tile(const bf16_t* g, int ld, int row0, int col0,
                                           bf16_t* lds, int tid) {
    int w = tid >> 6, l = tid & 63;
#pragma unroll
    for (int i = 0; i < 4; ++i) {
        int chunk = (i << 2) + w;
        int e = (chunk << 9) + (l << 3);
        int r = e >> 6, c = e & 63;
        const bf16_t* ga = g + (long)(row0 + r) * ld + col0 + c;
        bf16_t* la = lds + (chunk << 9);
        __builtin_amdgcn_global_load_lds((const GLOBAL_AS unsigned int*)ga,
                                         (LDS_AS unsigned int*)la, 16, 0, 0);
    }
}

template<int EPI>  // 0: bias+gelu -> bf16 ; 1: bias -> fp32
__global__ __launch_bounds__(256, 3) void gemm_bt(const bf16_t* __restrict__ A,
                                                  const bf16_t* __restrict__ Bt,
                                                  const float* __restrict__ bias,
                                                  void* __restrict__ Cout,
                                                  int M, int N, int K) {
    __shared__ __align__(16) bf16_t lA[128*64];
    __shared__ __align__(16) bf16_t lB[128*64];
    const int tid = threadIdx.x;
    const int l = tid & 63, w = tid >> 6;
    const int wr = w >> 1, wc = w & 1;
    const int row0 = blockIdx.y * 128, col0 = blockIdx.x * 128;
    f32x4 acc[4][4] = {};
    for (int k0 = 0; k0 < K; k0 += 64) {
        stage_tile(A,  K, row0, k0, lA, tid);
        stage_tile(Bt, K, col0, k0, lB, tid);
        __syncthreads();
#pragma unroll
        for (int kk = 0; kk < 64; kk += 32) {
            bf8 af[4], bfr[4];
            const int lr = l & 15, lk = kk + ((l >> 4) << 3);
#pragma unroll
            for (int mi = 0; mi < 4; ++mi)
                af[mi] = *(const bf8*)&lA[(wr*64 + mi*16 + lr)*64 + lk];
#pragma unroll
            for (int ni = 0; ni < 4; ++ni)
                bfr[ni] = *(const bf8*)&lB[(wc*64 + ni*16 + lr)*64 + lk];
#pragma unroll
            for (int mi = 0; mi < 4; ++mi)
#pragma unroll
                for (int ni = 0; ni < 4; ++ni)
                    acc[mi][ni] = __builtin_amdgcn_mfma_f32_16x16x32_bf16(
                        af[mi], bfr[ni], acc[mi][ni], 0, 0, 0);
        }
        __syncthreads();
    }
    const int fr = l & 15, fq = l >> 4;
#pragma unroll
    for (int mi = 0; mi < 4; ++mi) {
#pragma unroll
        for (int ni = 0; ni < 4; ++ni) {
#pragma unroll
            for (int q = 0; q < 4; ++q) {
                int r = row0 + wr*64 + mi*16 + fq*4 + q;
                int c = col0 + wc*64 + ni*16 + fr;
                float v = acc[mi][ni][q] + bias[c];
                if constexpr (EPI == 0) {
                    v = 0.5f * v * (1.0f + erff(v * 0.70710678118654752f));
                    ((bf16_t*)Cout)[(long)r * N + c] = (bf16_t)v;
                } else {
                    ((float*)Cout)[(long)r * N + c] = v;
                }
            }
        }
    }
}

// ---------------- 256x256 MFMA GEMM, 4-window schedule ----------------
// Round-5: __launch_bounds__(512, 1). The previous (512,2) capped the unified
// register file at 256/wave; the kernel needs ~296 live (acc 128 + operand
// frags 128 + addr ~40), so the compiler shuttled operands through AGPRs —
// ~8 VALU moves per MFMA, matching the measured 27% VALUBusy / 16% MfmaUtil.
// Occupancy is LDS-bound at 2 waves/SIMD regardless, so the cap bought nothing.

__device__ __forceinline__ void stage_half(const bf16_t* __restrict__ g, int ldK,
                                           long grow0, int k0, char* lds,
                                           int wid, int lane) {
    int r8 = lane >> 3;                       // row within 8-row chunk
    int cg = ((lane & 7) ^ r8) << 3;          // pre-swizzled element col (0..56)
#pragma unroll
    for (int j = 0; j < 2; ++j) {
        int chunk = j*8 + wid;                // 16 x 1KiB chunks per half-tile
        const bf16_t* ga = g + (grow0 + chunk*8 + r8) * (long)ldK + (k0 + cg);
        __builtin_amdgcn_global_load_lds((const GLOBAL_AS unsigned int*)ga,
                                         (LDS_AS unsigned int*)(lds + chunk*1024),
                                         16, 0, 0);
    }
}

template<int EPI>
__global__ __launch_bounds__(512, 1) void gemm256(const bf16_t* __restrict__ A,
                                                  const bf16_t* __restrict__ Bt,
                                                  const float* __restrict__ bias,
                                                  void* __restrict__ Cout,
                                                  int M, int N, int K, int TN) {
    __shared__ __align__(16) char smem[131072];
    const int tid = threadIdx.x;
    const int lane = tid & 63, wid = tid >> 6;
    const int wr = wid >> 2, wc = wid & 3;
    const int lr = lane & 15, lq = lane >> 4;

    // bijective XCD swizzle (grid is a multiple of 8)
    int cpx = gridDim.x >> 3;
    int bid = blockIdx.x;
    int swz = (bid & 7) * cpx + (bid >> 3);
    const long row0 = (long)(swz / TN) * 256;
    const long col0 = (long)(swz % TN) * 256;
    const int NT = K >> 6;

    // per-lane swizzled frag offsets (byte, within a 16 KiB half-tile)
    const int xr  = (lr & 7) << 4;
    const int kA0 = lr*128 + ((lq*16) ^ xr);          // kk=0
    const int kA1 = lr*128 + ((64 + lq*16) ^ xr);     // kk=32

    bf8 aL[4][2], aH[4][2], bL[2][2], bH[2][2];
    f32x4 acc[8][4] = {};

#define LD8(X) (*(const bf8*)(smem + (X)))

    // prologue: tile0 all 4 halves
    stage_half(A,  K, row0,       0, smem + 0,     wid, lane);
    stage_half(A,  K, row0 + 128, 0, smem + 16384, wid, lane);
    stage_half(Bt, K, col0,       0, smem + 32768, wid, lane);
    stage_half(Bt, K, col0 + 128, 0, smem + 49152, wid, lane);
    asm volatile("s_waitcnt vmcnt(0)" ::: "memory");
    __builtin_amdgcn_s_barrier();

    for (int t = 0; t < NT; ++t) {
        const int bufb = (t & 1) << 16;
        const int nbuf = ((t + 1) & 1) << 16;
        const int ao = bufb + (wr << 14);
        const int bo = bufb + 32768 + ((wc >> 1) << 14) + ((wc & 1) << 13);

        // ---- W0: stage ALL of tile t+1 ; read aL (P0), bL+bH (P0..P3) ----
        if (t + 1 < NT) {
            const int nk = (t + 1) << 6;
            stage_half(A,  K, row0,       nk, smem + nbuf,         wid, lane);
            stage_half(A,  K, row0 + 128, nk, smem + nbuf + 16384, wid, lane);
            stage_half(Bt, K, col0,       nk, smem + nbuf + 32768, wid, lane);
            stage_half(Bt, K, col0 + 128, nk, smem + nbuf + 49152, wid, lane);
        }
#pragma unroll
        for (int mi = 0; mi < 4; ++mi) {
            aL[mi][0] = LD8(ao + kA0 + mi*2048);
            aL[mi][1] = LD8(ao + kA1 + mi*2048);
        }
#pragma unroll
        for (int ni = 0; ni < 2; ++ni) {
            bL[ni][0] = LD8(bo + kA0 + ni*2048);
            bL[ni][1] = LD8(bo + kA1 + ni*2048);
            bH[ni][0] = LD8(bo + kA0 + (ni+2)*2048);
            bH[ni][1] = LD8(bo + kA1 + (ni+2)*2048);
        }
        __builtin_amdgcn_s_barrier();

        // ---- P0: mi0-3 x ni0-1 ----
        __builtin_amdgcn_s_setprio(1);
#pragma unroll
        for (int mi = 0; mi < 4; ++mi)
#pragma unroll
            for (int ni = 0; ni < 2; ++ni)
#pragma unroll
                for (int k = 0; k < 2; ++k)
                    acc[mi][ni] = __builtin_amdgcn_mfma_f32_16x16x32_bf16(
                        aL[mi][k], bL[ni][k], acc[mi][ni], 0, 0, 0);
        __builtin_amdgcn_s_setprio(0);
        __builtin_amdgcn_s_barrier();

        // ---- W1: read aH (P2/P3 operands) ----
#pragma unroll
        for (int mi = 0; mi < 4; ++mi) {
            aH[mi][0] = LD8(ao + kA0 + (mi+4)*2048);
            aH[mi][1] = LD8(ao + kA1 + (mi+4)*2048);
        }
        __builtin_amdgcn_s_barrier();

        // ---- P1 + P2 + P3 (aH reads drain under P1) ----
        __builtin_amdgcn_s_setprio(1);
#pragma unroll
        for (int mi = 0; mi < 4; ++mi)
#pragma unroll
            for (int ni = 0; ni < 2; ++ni)
#pragma unroll
                for (int k = 0; k < 2; ++k)
                    acc[mi][2+ni] = __builtin_amdgcn_mfma_f32_16x16x32_bf16(
                        aL[mi][k], bH[ni][k], acc[mi][2+ni], 0, 0, 0);
#pragma unroll
        for (int mi = 0; mi < 4; ++mi)
#pragma unroll
            for (int ni = 0; ni < 2; ++ni)
#pragma unroll
                for (int k = 0; k < 2; ++k)
                    acc[4+mi][2+ni] = __builtin_amdgcn_mfma_f32_16x16x32_bf16(
                        aH[mi][k], bH[ni][k], acc[4+mi][2+ni], 0, 0, 0);
#pragma unroll
        for (int mi = 0; mi < 4; ++mi)
#pragma unroll
            for (int ni = 0; ni < 2; ++ni)
#pragma unroll
                for (int k = 0; k < 2; ++k)
                    acc[4+mi][ni] = __builtin_amdgcn_mfma_f32_16x16x32_bf16(
                        aH[mi][k], bL[ni][k], acc[4+mi][ni], 0, 0, 0);
        __builtin_amdgcn_s_setprio(0);
        // fence: all staging done before any wave reads nbuf next tile
        asm volatile("s_waitcnt vmcnt(0)" ::: "memory");
        __builtin_amdgcn_s_barrier();
    }
#undef LD8

    // ---- epilogue ----
#pragma unroll
    for (int mi = 0; mi < 8; ++mi) {
#pragma unroll
        for (int ni = 0; ni < 4; ++ni) {
            long c = col0 + wc*64 + ni*16 + lr;
            float bv = bias[c];
#pragma unroll
            for (int q = 0; q < 4; ++q) {
                long r = row0 + wr*128 + mi*16 + lq*4 + q;
                float v = acc[mi][ni][q] + bv;
                if constexpr (EPI == 0) {
                    v = 0.5f * v * (1.0f + erff(v * 0.70710678118654752f));
                    ((bf16_t*)Cout)[r * N + c] = (bf16_t)v;
                } else {
                    ((float*)Cout)[r * N + c] = v;
                }
            }
        }
    }
}

// ---------------- launch ----------------

extern "C" void kernel_launch(void* const* d_in, const int* in_sizes, int n_in,
                              void* d_out, int out_size, void* d_ws, size_t ws_size,
                              hipStream_t stream) {
    const float* x        = (const float*)d_in[0];
    const float* fc_cr    = (const float*)d_in[1];
    const float* fc_ci    = (const float*)d_in[2];
    const int*   fc_idx   = (const int*)  d_in[3];
    const float* fc_scale = (const float*)d_in[4];
    const float* fc_bias  = (const float*)d_in[5];
    const float* pj_cr    = (const float*)d_in[6];
    const float* pj_ci    = (const float*)d_in[7];
    const int*   pj_idx   = (const int*)  d_in[8];
    const float* pj_scale = (const float*)d_in[9];
    const float* pj_bias  = (const float*)d_in[10];
    const int keep = in_sizes[1];

    char* ws = (char*)d_ws;
    bf16_t* w_fcT = (bf16_t*)(ws + 0);          //  8 MiB  [4096][1024]
    bf16_t* w_pjT = (bf16_t*)(ws + 8388608);    //  8 MiB  [1024][4096]
    bf16_t* x_bf  = (bf16_t*)(ws + 16777216);   // 16 MiB  [8192][1024]
    bf16_t* h_bf  = (bf16_t*)(ws + 33554432);   // 64 MiB  [8192][4096]
    float2* spec  = (float2*)(ws + 33554432);   // FFT scratch aliases h region
    float2* fftA  = (float2*)(ws + 50331904);
    float2* fftB  = (float2*)(ws + 67109120);

    auto run_decompress = [&](const float* cr, const float* ci, const int* idx,
                              const float* scale, bf16_t* wT, int R, int C) {
        zero2_kernel<<<(M_HALF + 1 + 255)/256, 256, 0, stream>>>(spec, M_HALF + 1);
        scatter_kernel<<<(keep + 255)/256, 256, 0, stream>>>(cr, ci, idx, spec, keep);
        prep_kernel<<<M_HALF/256, 256, 0, stream>>>(spec, fftA, scale);
        ifft_pass8<1>     <<<NQ/256, 256, 0, stream>>>(fftA, fftB);
        ifft_pass8<8>     <<<NQ/256, 256, 0, stream>>>(fftB, fftA);
        ifft_pass8<64>    <<<NQ/256, 256, 0, stream>>>(fftA, fftB);
        ifft_pass8<512>   <<<NQ/256, 256, 0, stream>>>(fftB, fftA);
        ifft_pass8<4096>  <<<NQ/256, 256, 0, stream>>>(fftA, fftB);
        ifft_pass8<32768> <<<NQ/256, 256, 0, stream>>>(fftB, fftA);
        ifft_pass8<262144><<<NQ/256, 256, 0, stream>>>(fftA, fftB);
        dim3 tg(C/32, R/32);
        transpose_kernel<<<tg, 256, 0, stream>>>((const float*)fftB, wT, R, C);
    };

    run_decompress(fc_cr, fc_ci, fc_idx, fc_scale, w_fcT, 1024, 4096);
    run_decompress(pj_cr, pj_ci, pj_idx, pj_scale, w_pjT, 4096, 1024);

    cvt_bf16_kernel<<<8388608/4/256, 256, 0, stream>>>(x, x_bf, 8388608/4);

    // GEMM1: 256^2 kernel. grid = (8192/256)*(4096/256) = 32*16 = 512
    gemm256<0><<<dim3(512), dim3(512), 0, stream>>>(
        x_bf, w_fcT, fc_bias, h_bf, 8192, 4096, 1024, 16);

    // GEMM2: 128^2 kernel (grid 8x64)
    gemm_bt<1><<<dim3(1024/128, 8192/128), 256, 0, stream>>>(
        h_bf, w_pjT, pj_bias, d_out, 8192, 1024, 4096);

    (void)n_in; (void)out_size; (void)ws_size;
}

// Round 6
// 344.705 us; speedup vs baseline: 1.2371x; 1.2098x over previous
//
#include <hip/hip_runtime.h>
#include <hip/hip_bf16.h>
#include <math.h>

#define M_HALF 2097152          // 2^21, half-length complex IFFT size
#define NQ     262144           // M_HALF / 8, threads per FFT pass

typedef __bf16 bf16_t;
typedef __attribute__((ext_vector_type(8))) __bf16 bf8;
typedef __attribute__((ext_vector_type(4))) __bf16 bf4;
typedef __attribute__((ext_vector_type(4))) float f32x4;

#define GLOBAL_AS __attribute__((address_space(1)))
#define LDS_AS    __attribute__((address_space(3)))

__device__ __forceinline__ float2 cadd(float2 a, float2 b){ return make_float2(a.x+b.x, a.y+b.y); }
__device__ __forceinline__ float2 csub(float2 a, float2 b){ return make_float2(a.x-b.x, a.y-b.y); }
__device__ __forceinline__ float2 cmul(float2 a, float2 b){ return make_float2(a.x*b.x-a.y*b.y, a.x*b.y+a.y*b.x); }
__device__ __forceinline__ float2 cmuli(float2 a){ return make_float2(-a.y, a.x); } // *(+i)

// ---------------- zero / scatter / preprocess ----------------

__global__ __launch_bounds__(256) void zero2_kernel(float2* p, int n) {
    int i = blockIdx.x*256 + threadIdx.x;
    if (i < n) p[i] = make_float2(0.f, 0.f);
}

__global__ __launch_bounds__(256) void scatter_kernel(const float* __restrict__ cr,
                                                      const float* __restrict__ ci,
                                                      const int* __restrict__ idx,
                                                      float2* __restrict__ spec, int keep) {
    int i = blockIdx.x*256 + threadIdx.x;
    if (i < keep) {
        int k = idx[i];
        spec[k] = make_float2(cr[i], ci[i]);
    }
}

__global__ __launch_bounds__(256) void prep_kernel(const float2* __restrict__ spec,
                                                   float2* __restrict__ Z,
                                                   const float* __restrict__ scale) {
    int k = blockIdx.x*256 + threadIdx.x;
    float2 a = spec[k];
    float2 b = spec[M_HALF - k];
    if (k == 0) { a.y = 0.0f; b.y = 0.0f; }   // c2r ignores imag of DC & Nyquist
    float Er = 0.5f*(a.x + b.x), Ei = 0.5f*(a.y - b.y);
    float Tr = 0.5f*(a.x - b.x), Ti = 0.5f*(a.y + b.y);
    float ang = (float)(3.14159265358979323846 * (double)k / (double)M_HALF);
    float sn, cs; sincosf(ang, &sn, &cs);
    float Or = Tr*cs - Ti*sn;
    float Oi = Tr*sn + Ti*cs;
    float s = scale[0] * (1.0f/(float)M_HALF);
    Z[k] = make_float2((Er - Oi)*s, (Ei + Or)*s);
}

// ---------------- radix-8 Stockham inverse FFT pass ----------------
template<int NS>
__global__ __launch_bounds__(256) void ifft_pass8(const float2* __restrict__ src,
                                                  float2* __restrict__ dst) {
    int j = blockIdx.x*256 + threadIdx.x;   // j < NQ
    float2 v[8];
#pragma unroll
    for (int t = 0; t < 8; ++t) v[t] = src[j + t*NQ];
    int jm = j & (NS - 1);
    if constexpr (NS > 1) {
        double base = (double)jm / (double)(NS * 8);
#pragma unroll
        for (int t = 1; t < 8; ++t) {
            float ang = (float)(6.283185307179586 * base * (double)t);
            float sn, cs; sincosf(ang, &sn, &cs);
            v[t] = cmul(v[t], make_float2(cs, sn));
        }
    }
    const float cc = 0.70710678118654752f;
    float2 a0 = cadd(v[0], v[4]), a1 = cadd(v[1], v[5]), a2 = cadd(v[2], v[6]), a3 = cadd(v[3], v[7]);
    float2 b0 = csub(v[0], v[4]), b1 = csub(v[1], v[5]), b2 = csub(v[2], v[6]), b3 = csub(v[3], v[7]);
    b1 = cmul(b1, make_float2(cc, cc));
    b2 = cmuli(b2);
    b3 = cmul(b3, make_float2(-cc, cc));
    float2 c0 = cadd(a0, a2), c1 = cadd(a1, a3), d0 = csub(a0, a2), d1 = cmuli(csub(a1, a3));
    float2 e0 = cadd(b0, b2), e1 = cadd(b1, b3), f0 = csub(b0, b2), f1 = cmuli(csub(b1, b3));
    float2 X0 = cadd(c0, c1), X4 = csub(c0, c1), X2 = cadd(d0, d1), X6 = csub(d0, d1);
    float2 X1 = cadd(e0, e1), X5 = csub(e0, e1), X3 = cadd(f0, f1), X7 = csub(f0, f1);
    int idxD = ((j - jm) << 3) + jm;
    dst[idxD + 0*NS] = X0;
    dst[idxD + 1*NS] = X1;
    dst[idxD + 2*NS] = X2;
    dst[idxD + 3*NS] = X3;
    dst[idxD + 4*NS] = X4;
    dst[idxD + 5*NS] = X5;
    dst[idxD + 6*NS] = X6;
    dst[idxD + 7*NS] = X7;
}

// ---------------- transpose fp32 -> bf16 (w[R][C] -> wT[C][R]) ----------------

__global__ __launch_bounds__(256) void transpose_kernel(const float* __restrict__ w,
                                                        bf16_t* __restrict__ wT,
                                                        int R, int C) {
    __shared__ float tile[32][33];
    int tx = threadIdx.x & 31, ty = threadIdx.x >> 5;
    long c0 = (long)blockIdx.x * 32, r0 = (long)blockIdx.y * 32;
#pragma unroll
    for (int i = 0; i < 4; ++i)
        tile[ty + i*8][tx] = w[(r0 + ty + i*8) * C + c0 + tx];
    __syncthreads();
#pragma unroll
    for (int i = 0; i < 4; ++i) {
        int c = ty + i*8;
        wT[(c0 + c) * R + r0 + tx] = (bf16_t)tile[tx][c];
    }
}

// ---------------- fp32 -> bf16 convert (x) ----------------

__global__ __launch_bounds__(256) void cvt_bf16_kernel(const float* __restrict__ in,
                                                       bf16_t* __restrict__ out, int n4) {
    int i = blockIdx.x*256 + threadIdx.x;
    if (i < n4) {
        float4 v = ((const float4*)in)[i];
        bf4 o;
        o[0] = (bf16_t)v.x; o[1] = (bf16_t)v.y; o[2] = (bf16_t)v.z; o[3] = (bf16_t)v.w;
        ((bf4*)out)[i] = o;
    }
}

// ---------------- 128-tile MFMA GEMM, XOR-swizzled LDS ----------------
// Round-6: (a) __launch_bounds__(256,3) = m97's regalloc point (round-1 bare
// bound squeezed to 88 VGPR); (b) LDS tile [128][64] bf16 stored with the
// verified involution  LDS[row][cb] = G[row][cb ^ ((row&7)<<4)]  (16B granules):
// staged via pre-swizzled GLOBAL source (linear global_load_lds dest, rule 21),
// read via the same XOR. Kills the 16-way ds_read_b128 conflict (2.5e7 -> ~0).

__device__ __forceinline__ void stage_tile_sw(const bf16_t* g, int ld, int row0, int col0,
                                              bf16_t* lds, int tid) {
    int w = tid >> 6, l = tid & 63;
    int r8 = l >> 3;                       // row within 8-row chunk
    int cg = ((l & 7) ^ r8) << 3;          // pre-swizzled element col (0..56)
#pragma unroll
    for (int i = 0; i < 4; ++i) {
        int chunk = (i << 2) + w;          // 16 chunks x 8 rows x 64 cols
        const bf16_t* ga = g + (long)(row0 + chunk*8 + r8) * ld + col0 + cg;
        bf16_t* la = lds + (chunk << 9);   // wave-uniform LDS base, linear dest
        __builtin_amdgcn_global_load_lds((const GLOBAL_AS unsigned int*)ga,
                                         (LDS_AS unsigned int*)la, 16, 0, 0);
    }
}

template<int EPI>  // 0: bias+gelu -> bf16 ; 1: bias -> fp32
__global__ __launch_bounds__(256, 3) void gemm_bt(const bf16_t* __restrict__ A,
                                                  const bf16_t* __restrict__ Bt,
                                                  const float* __restrict__ bias,
                                                  void* __restrict__ Cout,
                                                  int M, int N, int K) {
    __shared__ __align__(16) bf16_t lA[128*64];
    __shared__ __align__(16) bf16_t lB[128*64];
    const int tid = threadIdx.x;
    const int l = tid & 63, w = tid >> 6;
    const int wr = w >> 1, wc = w & 1;
    const int row0 = blockIdx.y * 128, col0 = blockIdx.x * 128;
    const int lr = l & 15, lq = l >> 4;
    const int xr = (lr & 7) << 4;                  // swizzle byte XOR
    f32x4 acc[4][4] = {};
    for (int k0 = 0; k0 < K; k0 += 64) {
        stage_tile_sw(A,  K, row0, k0, lA, tid);
        stage_tile_sw(Bt, K, col0, k0, lB, tid);
        __syncthreads();
#pragma unroll
        for (int kk = 0; kk < 2; ++kk) {           // kk: 0 -> byte 0, 1 -> byte 64
            bf8 af[4], bfr[4];
            const int kb = ((kk << 6) + lq*16) ^ xr;
#pragma unroll
            for (int mi = 0; mi < 4; ++mi)
                af[mi] = *(const bf8*)((const char*)lA + (wr*64 + mi*16 + lr)*128 + kb);
#pragma unroll
            for (int ni = 0; ni < 4; ++ni)
                bfr[ni] = *(const bf8*)((const char*)lB + (wc*64 + ni*16 + lr)*128 + kb);
#pragma unroll
            for (int mi = 0; mi < 4; ++mi)
#pragma unroll
                for (int ni = 0; ni < 4; ++ni)
                    acc[mi][ni] = __builtin_amdgcn_mfma_f32_16x16x32_bf16(
                        af[mi], bfr[ni], acc[mi][ni], 0, 0, 0);
        }
        __syncthreads();
    }
    const int fr = lr, fq = lq;
#pragma unroll
    for (int mi = 0; mi < 4; ++mi) {
#pragma unroll
        for (int ni = 0; ni < 4; ++ni) {
#pragma unroll
            for (int q = 0; q < 4; ++q) {
                int r = row0 + wr*64 + mi*16 + fq*4 + q;
                int c = col0 + wc*64 + ni*16 + fr;
                float v = acc[mi][ni][q] + bias[c];
                if constexpr (EPI == 0) {
                    v = 0.5f * v * (1.0f + erff(v * 0.70710678118654752f));
                    ((bf16_t*)Cout)[(long)r * N + c] = (bf16_t)v;
                } else {
                    ((float*)Cout)[(long)r * N + c] = v;
                }
            }
        }
    }
}

// ---------------- launch ----------------

extern "C" void kernel_launch(void* const* d_in, const int* in_sizes, int n_in,
                              void* d_out, int out_size, void* d_ws, size_t ws_size,
                              hipStream_t stream) {
    const float* x        = (const float*)d_in[0];
    const float* fc_cr    = (const float*)d_in[1];
    const float* fc_ci    = (const float*)d_in[2];
    const int*   fc_idx   = (const int*)  d_in[3];
    const float* fc_scale = (const float*)d_in[4];
    const float* fc_bias  = (const float*)d_in[5];
    const float* pj_cr    = (const float*)d_in[6];
    const float* pj_ci    = (const float*)d_in[7];
    const int*   pj_idx   = (const int*)  d_in[8];
    const float* pj_scale = (const float*)d_in[9];
    const float* pj_bias  = (const float*)d_in[10];
    const int keep = in_sizes[1];

    char* ws = (char*)d_ws;
    bf16_t* w_fcT = (bf16_t*)(ws + 0);          //  8 MiB  [4096][1024]
    bf16_t* w_pjT = (bf16_t*)(ws + 8388608);    //  8 MiB  [1024][4096]
    bf16_t* x_bf  = (bf16_t*)(ws + 16777216);   // 16 MiB  [8192][1024]
    bf16_t* h_bf  = (bf16_t*)(ws + 33554432);   // 64 MiB  [8192][4096]
    float2* spec  = (float2*)(ws + 33554432);   // FFT scratch aliases h region
    float2* fftA  = (float2*)(ws + 50331904);
    float2* fftB  = (float2*)(ws + 67109120);

    auto run_decompress = [&](const float* cr, const float* ci, const int* idx,
                              const float* scale, bf16_t* wT, int R, int C) {
        zero2_kernel<<<(M_HALF + 1 + 255)/256, 256, 0, stream>>>(spec, M_HALF + 1);
        scatter_kernel<<<(keep + 255)/256, 256, 0, stream>>>(cr, ci, idx, spec, keep);
        prep_kernel<<<M_HALF/256, 256, 0, stream>>>(spec, fftA, scale);
        ifft_pass8<1>     <<<NQ/256, 256, 0, stream>>>(fftA, fftB);
        ifft_pass8<8>     <<<NQ/256, 256, 0, stream>>>(fftB, fftA);
        ifft_pass8<64>    <<<NQ/256, 256, 0, stream>>>(fftA, fftB);
        ifft_pass8<512>   <<<NQ/256, 256, 0, stream>>>(fftB, fftA);
        ifft_pass8<4096>  <<<NQ/256, 256, 0, stream>>>(fftA, fftB);
        ifft_pass8<32768> <<<NQ/256, 256, 0, stream>>>(fftB, fftA);
        ifft_pass8<262144><<<NQ/256, 256, 0, stream>>>(fftA, fftB);
        dim3 tg(C/32, R/32);
        transpose_kernel<<<tg, 256, 0, stream>>>((const float*)fftB, wT, R, C);
    };

    run_decompress(fc_cr, fc_ci, fc_idx, fc_scale, w_fcT, 1024, 4096);
    run_decompress(pj_cr, pj_ci, pj_idx, pj_scale, w_pjT, 4096, 1024);

    cvt_bf16_kernel<<<8388608/4/256, 256, 0, stream>>>(x, x_bf, 8388608/4);

    // GEMM1: 128^2 tiles, grid = (4096/128) x (8192/128) = 32 x 64 = 2048
    gemm_bt<0><<<dim3(4096/128, 8192/128), 256, 0, stream>>>(
        x_bf, w_fcT, fc_bias, h_bf, 8192, 4096, 1024);

    // GEMM2: 128^2 tiles, grid = 8 x 64 = 512
    gemm_bt<1><<<dim3(1024/128, 8192/128), 256, 0, stream>>>(
        h_bf, w_pjT, pj_bias, d_out, 8192, 1024, 4096);

    (void)n_in; (void)out_size; (void)ws_size;
}

// Round 7
// 274.185 us; speedup vs baseline: 1.5553x; 1.2572x over previous
//
#include <hip/hip_runtime.h>
#include <hip/hip_bf16.h>
#include <math.h>

#define M_HALF 2097152          // 2^21, half-length complex IFFT size
#define NQ     262144           // M_HALF / 8, threads per radix-8 pass
#define M64    32768            // M_HALF / 64

typedef __bf16 bf16_t;
typedef __attribute__((ext_vector_type(8))) __bf16 bf8;
typedef __attribute__((ext_vector_type(4))) __bf16 bf4;
typedef __attribute__((ext_vector_type(4))) float f32x4;

#define GLOBAL_AS __attribute__((address_space(1)))
#define LDS_AS    __attribute__((address_space(3)))

__device__ __forceinline__ float2 cadd(float2 a, float2 b){ return make_float2(a.x+b.x, a.y+b.y); }
__device__ __forceinline__ float2 csub(float2 a, float2 b){ return make_float2(a.x-b.x, a.y-b.y); }
__device__ __forceinline__ float2 cmul(float2 a, float2 b){ return make_float2(a.x*b.x-a.y*b.y, a.x*b.y+a.y*b.x); }
__device__ __forceinline__ float2 cmuli(float2 a){ return make_float2(-a.y, a.x); } // *(+i)

// inverse 8-point DFT (positive exponent), natural order
__device__ __forceinline__ void radix8_inv(const float2 v[8], float2 X[8]) {
    const float cc = 0.70710678118654752f;
    float2 a0 = cadd(v[0], v[4]), a1 = cadd(v[1], v[5]), a2 = cadd(v[2], v[6]), a3 = cadd(v[3], v[7]);
    float2 b0 = csub(v[0], v[4]), b1 = csub(v[1], v[5]), b2 = csub(v[2], v[6]), b3 = csub(v[3], v[7]);
    b1 = cmul(b1, make_float2(cc, cc));
    b2 = cmuli(b2);
    b3 = cmul(b3, make_float2(-cc, cc));
    float2 c0 = cadd(a0, a2), c1 = cadd(a1, a3), d0 = csub(a0, a2), d1 = cmuli(csub(a1, a3));
    float2 e0 = cadd(b0, b2), e1 = cadd(b1, b3), f0 = csub(b0, b2), f1 = cmuli(csub(b1, b3));
    X[0] = cadd(c0, c1); X[4] = csub(c0, c1); X[2] = cadd(d0, d1); X[6] = csub(d0, d1);
    X[1] = cadd(e0, e1); X[5] = csub(e0, e1); X[3] = cadd(f0, f1); X[7] = csub(f0, f1);
}

// ---------------- zero / scatter ----------------

__global__ __launch_bounds__(256) void zero2_kernel(float2* p, int n) {
    int i = blockIdx.x*256 + threadIdx.x;
    if (i < n) p[i] = make_float2(0.f, 0.f);
}

__global__ __launch_bounds__(256) void scatter_kernel(const float* __restrict__ cr,
                                                      const float* __restrict__ ci,
                                                      const int* __restrict__ idx,
                                                      float2* __restrict__ spec, int keep) {
    int i = blockIdx.x*256 + threadIdx.x;
    if (i < keep) {
        int k = idx[i];
        spec[k] = make_float2(cr[i], ci[i]);
    }
}

// ---------------- radix-64 Stockham inverse FFT pass (two radix-8 + LDS) ----
// Y[s] = sum_t v[t] e^{+2pi i jm t/(64 NS)} e^{+2pi i s t/64};
// dst[64(jg-jm) + jm + s*NS].  FIRST fuses the rfft->half-size-complex prep
// (NS==1 there, so no outer twiddle).
template<int NS, bool FIRST>
__global__ __launch_bounds__(256) void ifft_pass64(const float2* __restrict__ src,
                                                   float2* __restrict__ dst,
                                                   const float2* __restrict__ spec,
                                                   const float* __restrict__ scale) {
    __shared__ float2 ex[32][65];
    const int tid = threadIdx.x;
    const int x = tid >> 5, gl = tid & 31;
    const int jg = blockIdx.x * 32 + gl;
    const int jm = jg & (NS - 1);
    float2 v[8];
    if constexpr (FIRST) {
        float s = scale[0] * (1.0f/(float)M_HALF);
#pragma unroll
        for (int u = 0; u < 8; ++u) {
            int k = jg + (x + 8*u) * M64;
            float2 a = spec[k];
            float2 b = spec[M_HALF - k];
            if (k == 0) { a.y = 0.0f; b.y = 0.0f; }
            float Er = 0.5f*(a.x + b.x), Ei = 0.5f*(a.y - b.y);
            float Tr = 0.5f*(a.x - b.x), Ti = 0.5f*(a.y + b.y);
            float ang = (float)(3.14159265358979323846 * (double)k / (double)M_HALF);
            float sn, cs; sincosf(ang, &sn, &cs);
            float Or = Tr*cs - Ti*sn, Oi = Tr*sn + Ti*cs;
            v[u] = make_float2((Er - Oi)*s, (Ei + Or)*s);
        }
    } else {
#pragma unroll
        for (int u = 0; u < 8; ++u)
            v[u] = src[jg + (x + 8*u) * M64];
        // outer twiddle e^{+i th (x+8u)}, th = 2pi jm/(64 NS); recurrence over u
        double th = 6.283185307179586 * (double)jm / (double)(NS * 64);
        float c0, s0, c8, s8;
        sincosf((float)(th * (double)x), &s0, &c0);
        sincosf((float)(th * 8.0), &s8, &c8);
        float2 w = make_float2(c0, s0), w8 = make_float2(c8, s8);
#pragma unroll
        for (int u = 0; u < 8; ++u) {
            v[u] = cmul(v[u], w);
            w = cmul(w, w8);
        }
    }
    float2 X[8];
    radix8_inv(v, X);
    {   // inner twiddle e^{+i pi x s2/32}, recurrence over s2; write exchange
        float cb, sb; sincosf((float)x * 0.09817477042468103f, &sb, &cb);
        float2 wb = make_float2(cb, sb), wc = make_float2(1.f, 0.f);
#pragma unroll
        for (int s2 = 0; s2 < 8; ++s2) {
            ex[gl][x*8 + s2] = cmul(X[s2], wc);
            wc = cmul(wc, wb);
        }
    }
    __syncthreads();
    float2 W2[8];
#pragma unroll
    for (int t1 = 0; t1 < 8; ++t1) W2[t1] = ex[gl][t1*8 + x];
    float2 Y[8];
    radix8_inv(W2, Y);               // output s = x + 8*s1
    if constexpr (NS == 1) {
        // reorg through LDS so global stores are linear 64B per lane
        __syncthreads();
#pragma unroll
        for (int s1 = 0; s1 < 8; ++s1) ex[gl][x + 8*s1] = Y[s1];
        __syncthreads();
        const long base = (long)blockIdx.x * 2048;
#pragma unroll
        for (int e = 0; e < 8; ++e) {
            int flat = tid*8 + e;
            dst[base + flat] = ex[flat >> 6][flat & 63];
        }
    } else {
        const long obase = (long)(jg - jm) * 64 + jm;
#pragma unroll
        for (int s1 = 0; s1 < 8; ++s1)
            dst[obase + (long)(x + 8*s1) * NS] = Y[s1];
    }
}

// ---------------- radix-8 Stockham inverse FFT pass (final) ----------------
template<int NS>
__global__ __launch_bounds__(256) void ifft_pass8(const float2* __restrict__ src,
                                                  float2* __restrict__ dst) {
    int j = blockIdx.x*256 + threadIdx.x;   // j < NQ
    float2 v[8];
#pragma unroll
    for (int t = 0; t < 8; ++t) v[t] = src[j + t*NQ];
    int jm = j & (NS - 1);
    if constexpr (NS > 1) {
        double base = (double)jm / (double)(NS * 8);
#pragma unroll
        for (int t = 1; t < 8; ++t) {
            float ang = (float)(6.283185307179586 * base * (double)t);
            float sn, cs; sincosf(ang, &sn, &cs);
            v[t] = cmul(v[t], make_float2(cs, sn));
        }
    }
    float2 X[8];
    radix8_inv(v, X);
    int idxD = ((j - jm) << 3) + jm;
#pragma unroll
    for (int s = 0; s < 8; ++s) dst[idxD + s*NS] = X[s];
}

// ---------------- transpose fp32 -> bf16 (w[R][C] -> wT[C][R]) ----------------

__global__ __launch_bounds__(256) void transpose_kernel(const float* __restrict__ w,
                                                        bf16_t* __restrict__ wT,
                                                        int R, int C) {
    __shared__ float tile[32][33];
    int tx = threadIdx.x & 31, ty = threadIdx.x >> 5;
    long c0 = (long)blockIdx.x * 32, r0 = (long)blockIdx.y * 32;
#pragma unroll
    for (int i = 0; i < 4; ++i)
        tile[ty + i*8][tx] = w[(r0 + ty + i*8) * C + c0 + tx];
    __syncthreads();
#pragma unroll
    for (int i = 0; i < 4; ++i) {
        int c = ty + i*8;
        wT[(c0 + c) * R + r0 + tx] = (bf16_t)tile[tx][c];
    }
}

// ---------------- fp32 -> bf16 convert (x) ----------------

__global__ __launch_bounds__(256) void cvt_bf16_kernel(const float* __restrict__ in,
                                                       bf16_t* __restrict__ out, int n4) {
    int i = blockIdx.x*256 + threadIdx.x;
    if (i < n4) {
        float4 v = ((const float4*)in)[i];
        bf4 o;
        o[0] = (bf16_t)v.x; o[1] = (bf16_t)v.y; o[2] = (bf16_t)v.z; o[3] = (bf16_t)v.w;
        ((bf4*)out)[i] = o;
    }
}

// ---------------- 128-tile MFMA GEMM, XOR-swizzled LDS (GEMM1, 4-wave) -------
// LDS[row][cb] = G[row][cb ^ ((row&7)<<4)] (16B granules): staged via
// pre-swizzled GLOBAL source (linear global_load_lds dest), read via same XOR.

__device__ __forceinline__ void stage_tile_sw(const bf16_t* g, int ld, int row0, int col0,
                                              bf16_t* lds, int tid) {
    int w = tid >> 6, l = tid & 63;
    int r8 = l >> 3;
    int cg = ((l & 7) ^ r8) << 3;
#pragma unroll
    for (int i = 0; i < 4; ++i) {
        int chunk = (i << 2) + w;          // 16 chunks x 8 rows x 64 cols
        const bf16_t* ga = g + (long)(row0 + chunk*8 + r8) * ld + col0 + cg;
        bf16_t* la = lds + (chunk << 9);
        __builtin_amdgcn_global_load_lds((const GLOBAL_AS unsigned int*)ga,
                                         (LDS_AS unsigned int*)la, 16, 0, 0);
    }
}

template<int EPI>  // 0: bias+gelu -> bf16 ; 1: bias -> fp32
__global__ __launch_bounds__(256, 3) void gemm_bt(const bf16_t* __restrict__ A,
                                                  const bf16_t* __restrict__ Bt,
                                                  const float* __restrict__ bias,
                                                  void* __restrict__ Cout,
                                                  int M, int N, int K) {
    __shared__ __align__(16) bf16_t lA[128*64];
    __shared__ __align__(16) bf16_t lB[128*64];
    const int tid = threadIdx.x;
    const int l = tid & 63, w = tid >> 6;
    const int wr = w >> 1, wc = w & 1;
    const int row0 = blockIdx.y * 128, col0 = blockIdx.x * 128;
    const int lr = l & 15, lq = l >> 4;
    const int xr = (lr & 7) << 4;
    f32x4 acc[4][4] = {};
    for (int k0 = 0; k0 < K; k0 += 64) {
        stage_tile_sw(A,  K, row0, k0, lA, tid);
        stage_tile_sw(Bt, K, col0, k0, lB, tid);
        __syncthreads();
#pragma unroll
        for (int kk = 0; kk < 2; ++kk) {
            bf8 af[4], bfr[4];
            const int kb = ((kk << 6) + lq*16) ^ xr;
#pragma unroll
            for (int mi = 0; mi < 4; ++mi)
                af[mi] = *(const bf8*)((const char*)lA + (wr*64 + mi*16 + lr)*128 + kb);
#pragma unroll
            for (int ni = 0; ni < 4; ++ni)
                bfr[ni] = *(const bf8*)((const char*)lB + (wc*64 + ni*16 + lr)*128 + kb);
#pragma unroll
            for (int mi = 0; mi < 4; ++mi)
#pragma unroll
                for (int ni = 0; ni < 4; ++ni)
                    acc[mi][ni] = __builtin_amdgcn_mfma_f32_16x16x32_bf16(
                        af[mi], bfr[ni], acc[mi][ni], 0, 0, 0);
        }
        __syncthreads();
    }
#pragma unroll
    for (int mi = 0; mi < 4; ++mi) {
#pragma unroll
        for (int ni = 0; ni < 4; ++ni) {
#pragma unroll
            for (int q = 0; q < 4; ++q) {
                int r = row0 + wr*64 + mi*16 + lq*4 + q;
                int c = col0 + wc*64 + ni*16 + lr;
                float v = acc[mi][ni][q] + bias[c];
                if constexpr (EPI == 0) {
                    v = 0.5f * v * (1.0f + erff(v * 0.70710678118654752f));
                    ((bf16_t*)Cout)[(long)r * N + c] = (bf16_t)v;
                } else {
                    ((float*)Cout)[(long)r * N + c] = v;
                }
            }
        }
    }
}

// ---------------- 128-tile GEMM, 8-wave variant (GEMM2) ----------------------
// Same tiles/swizzle; 512 threads (8 waves, 2Mx4N, per-wave 64x32 out,
// acc 4x2). Doubles waves/CU at GEMM2's grid-limited 2 blocks/CU.

__device__ __forceinline__ void stage_tile_sw8(const bf16_t* g, int ld, int row0, int col0,
                                               bf16_t* lds, int tid) {
    int w = tid >> 6, l = tid & 63;        // w in [0,8)
    int r8 = l >> 3;
    int cg = ((l & 7) ^ r8) << 3;
#pragma unroll
    for (int i = 0; i < 2; ++i) {
        int chunk = (i << 3) + w;          // 16 chunks
        const bf16_t* ga = g + (long)(row0 + chunk*8 + r8) * ld + col0 + cg;
        bf16_t* la = lds + (chunk << 9);
        __builtin_amdgcn_global_load_lds((const GLOBAL_AS unsigned int*)ga,
                                         (LDS_AS unsigned int*)la, 16, 0, 0);
    }
}

__global__ __launch_bounds__(512, 4) void gemm_bt8(const bf16_t* __restrict__ A,
                                                   const bf16_t* __restrict__ Bt,
                                                   const float* __restrict__ bias,
                                                   float* __restrict__ Cout,
                                                   int M, int N, int K) {
    __shared__ __align__(16) bf16_t lA[128*64];
    __shared__ __align__(16) bf16_t lB[128*64];
    const int tid = threadIdx.x;
    const int l = tid & 63, w = tid >> 6;
    const int wr = w >> 2, wc = w & 3;
    const int row0 = blockIdx.y * 128, col0 = blockIdx.x * 128;
    const int lr = l & 15, lq = l >> 4;
    const int xr = (lr & 7) << 4;
    f32x4 acc[4][2] = {};
    for (int k0 = 0; k0 < K; k0 += 64) {
        stage_tile_sw8(A,  K, row0, k0, lA, tid);
        stage_tile_sw8(Bt, K, col0, k0, lB, tid);
        __syncthreads();
#pragma unroll
        for (int kk = 0; kk < 2; ++kk) {
            bf8 af[4], bfr[2];
            const int kb = ((kk << 6) + lq*16) ^ xr;
#pragma unroll
            for (int mi = 0; mi < 4; ++mi)
                af[mi] = *(const bf8*)((const char*)lA + (wr*64 + mi*16 + lr)*128 + kb);
#pragma unroll
            for (int ni = 0; ni < 2; ++ni)
                bfr[ni] = *(const bf8*)((const char*)lB + (wc*32 + ni*16 + lr)*128 + kb);
#pragma unroll
            for (int mi = 0; mi < 4; ++mi)
#pragma unroll
                for (int ni = 0; ni < 2; ++ni)
                    acc[mi][ni] = __builtin_amdgcn_mfma_f32_16x16x32_bf16(
                        af[mi], bfr[ni], acc[mi][ni], 0, 0, 0);
        }
        __syncthreads();
    }
#pragma unroll
    for (int mi = 0; mi < 4; ++mi) {
#pragma unroll
        for (int ni = 0; ni < 2; ++ni) {
            int c = col0 + wc*32 + ni*16 + lr;
            float bv = bias[c];
#pragma unroll
            for (int q = 0; q < 4; ++q) {
                int r = row0 + wr*64 + mi*16 + lq*4 + q;
                Cout[(long)r * N + c] = acc[mi][ni][q] + bv;
            }
        }
    }
}

// ---------------- launch ----------------

extern "C" void kernel_launch(void* const* d_in, const int* in_sizes, int n_in,
                              void* d_out, int out_size, void* d_ws, size_t ws_size,
                              hipStream_t stream) {
    const float* x        = (const float*)d_in[0];
    const float* fc_cr    = (const float*)d_in[1];
    const float* fc_ci    = (const float*)d_in[2];
    const int*   fc_idx   = (const int*)  d_in[3];
    const float* fc_scale = (const float*)d_in[4];
    const float* fc_bias  = (const float*)d_in[5];
    const float* pj_cr    = (const float*)d_in[6];
    const float* pj_ci    = (const float*)d_in[7];
    const int*   pj_idx   = (const int*)  d_in[8];
    const float* pj_scale = (const float*)d_in[9];
    const float* pj_bias  = (const float*)d_in[10];
    const int keep = in_sizes[1];

    char* ws = (char*)d_ws;
    bf16_t* w_fcT = (bf16_t*)(ws + 0);          //  8 MiB  [4096][1024]
    bf16_t* w_pjT = (bf16_t*)(ws + 8388608);    //  8 MiB  [1024][4096]
    bf16_t* x_bf  = (bf16_t*)(ws + 16777216);   // 16 MiB  [8192][1024]
    bf16_t* h_bf  = (bf16_t*)(ws + 33554432);   // 64 MiB  [8192][4096]
    float2* spec  = (float2*)(ws + 33554432);   // FFT scratch aliases h region
    float2* fftA  = (float2*)(ws + 50331904);
    float2* fftB  = (float2*)(ws + 67109120);

    auto run_decompress = [&](const float* cr, const float* ci, const int* idx,
                              const float* scale, bf16_t* wT, int R, int C) {
        zero2_kernel<<<(M_HALF + 1 + 255)/256, 256, 0, stream>>>(spec, M_HALF + 1);
        scatter_kernel<<<(keep + 255)/256, 256, 0, stream>>>(cr, ci, idx, spec, keep);
        // radices: 64 (prep fused), 64, 64, 8  -> 2^21
        ifft_pass64<1, true>    <<<M64/32, 256, 0, stream>>>(fftA, fftA, spec, scale);
        ifft_pass64<64, false>  <<<M64/32, 256, 0, stream>>>(fftA, fftB, nullptr, nullptr);
        ifft_pass64<4096, false><<<M64/32, 256, 0, stream>>>(fftB, fftA, nullptr, nullptr);
        ifft_pass8<262144>      <<<NQ/256, 256, 0, stream>>>(fftA, fftB);
        dim3 tg(C/32, R/32);
        transpose_kernel<<<tg, 256, 0, stream>>>((const float*)fftB, wT, R, C);
    };

    run_decompress(fc_cr, fc_ci, fc_idx, fc_scale, w_fcT, 1024, 4096);
    run_decompress(pj_cr, pj_ci, pj_idx, pj_scale, w_pjT, 4096, 1024);

    cvt_bf16_kernel<<<8388608/4/256, 256, 0, stream>>>(x, x_bf, 8388608/4);

    // GEMM1: 128^2 tiles, grid = 32 x 64 = 2048 (control, unchanged)
    gemm_bt<0><<<dim3(4096/128, 8192/128), 256, 0, stream>>>(
        x_bf, w_fcT, fc_bias, h_bf, 8192, 4096, 1024);

    // GEMM2: 8-wave variant, grid = 8 x 64 = 512
    gemm_bt8<<<dim3(1024/128, 8192/128), 512, 0, stream>>>(
        h_bf, w_pjT, pj_bias, (float*)d_out, 8192, 1024, 4096);

    (void)n_in; (void)out_size; (void)ws_size;
}

// Round 8
// 271.397 us; speedup vs baseline: 1.5713x; 1.0103x over previous
//
#include <hip/hip_runtime.h>
#include <hip/hip_bf16.h>
#include <math.h>

#define M_HALF 2097152          // 2^21, half-length complex IFFT size
#define NQ     262144           // M_HALF / 8, threads per radix-8 pass
#define M64    32768            // M_HALF / 64

typedef __bf16 bf16_t;
typedef __attribute__((ext_vector_type(8))) __bf16 bf8;
typedef __attribute__((ext_vector_type(4))) __bf16 bf4;
typedef __attribute__((ext_vector_type(4))) float f32x4;

#define GLOBAL_AS __attribute__((address_space(1)))
#define LDS_AS    __attribute__((address_space(3)))

__device__ __forceinline__ float2 cadd(float2 a, float2 b){ return make_float2(a.x+b.x, a.y+b.y); }
__device__ __forceinline__ float2 csub(float2 a, float2 b){ return make_float2(a.x-b.x, a.y-b.y); }
__device__ __forceinline__ float2 cmul(float2 a, float2 b){ return make_float2(a.x*b.x-a.y*b.y, a.x*b.y+a.y*b.x); }
__device__ __forceinline__ float2 cmuli(float2 a){ return make_float2(-a.y, a.x); } // *(+i)

// inverse 8-point DFT (positive exponent), natural order
__device__ __forceinline__ void radix8_inv(const float2 v[8], float2 X[8]) {
    const float cc = 0.70710678118654752f;
    float2 a0 = cadd(v[0], v[4]), a1 = cadd(v[1], v[5]), a2 = cadd(v[2], v[6]), a3 = cadd(v[3], v[7]);
    float2 b0 = csub(v[0], v[4]), b1 = csub(v[1], v[5]), b2 = csub(v[2], v[6]), b3 = csub(v[3], v[7]);
    b1 = cmul(b1, make_float2(cc, cc));
    b2 = cmuli(b2);
    b3 = cmul(b3, make_float2(-cc, cc));
    float2 c0 = cadd(a0, a2), c1 = cadd(a1, a3), d0 = csub(a0, a2), d1 = cmuli(csub(a1, a3));
    float2 e0 = cadd(b0, b2), e1 = cadd(b1, b3), f0 = csub(b0, b2), f1 = cmuli(csub(b1, b3));
    X[0] = cadd(c0, c1); X[4] = csub(c0, c1); X[2] = cadd(d0, d1); X[6] = csub(d0, d1);
    X[1] = cadd(e0, e1); X[5] = csub(e0, e1); X[3] = cadd(f0, f1); X[7] = csub(f0, f1);
}

// ---------------- zero / scatter ----------------

__global__ __launch_bounds__(256) void zero2_kernel(float2* p, int n) {
    int i = blockIdx.x*256 + threadIdx.x;
    if (i < n) p[i] = make_float2(0.f, 0.f);
}

__global__ __launch_bounds__(256) void scatter_kernel(const float* __restrict__ cr,
                                                      const float* __restrict__ ci,
                                                      const int* __restrict__ idx,
                                                      float2* __restrict__ spec, int keep) {
    int i = blockIdx.x*256 + threadIdx.x;
    if (i < keep) {
        int k = idx[i];
        spec[k] = make_float2(cr[i], ci[i]);
    }
}

// ---------------- radix-64 Stockham inverse FFT pass (two radix-8 + LDS) ----
template<int NS, bool FIRST>
__global__ __launch_bounds__(256) void ifft_pass64(const float2* __restrict__ src,
                                                   float2* __restrict__ dst,
                                                   const float2* __restrict__ spec,
                                                   const float* __restrict__ scale) {
    __shared__ float2 ex[32][65];
    const int tid = threadIdx.x;
    const int x = tid >> 5, gl = tid & 31;
    const int jg = blockIdx.x * 32 + gl;
    const int jm = jg & (NS - 1);
    float2 v[8];
    if constexpr (FIRST) {
        float s = scale[0] * (1.0f/(float)M_HALF);
#pragma unroll
        for (int u = 0; u < 8; ++u) {
            int k = jg + (x + 8*u) * M64;
            float2 a = spec[k];
            float2 b = spec[M_HALF - k];
            if (k == 0) { a.y = 0.0f; b.y = 0.0f; }
            float Er = 0.5f*(a.x + b.x), Ei = 0.5f*(a.y - b.y);
            float Tr = 0.5f*(a.x - b.x), Ti = 0.5f*(a.y + b.y);
            float ang = (float)(3.14159265358979323846 * (double)k / (double)M_HALF);
            float sn, cs; sincosf(ang, &sn, &cs);
            float Or = Tr*cs - Ti*sn, Oi = Tr*sn + Ti*cs;
            v[u] = make_float2((Er - Oi)*s, (Ei + Or)*s);
        }
    } else {
#pragma unroll
        for (int u = 0; u < 8; ++u)
            v[u] = src[jg + (x + 8*u) * M64];
        double th = 6.283185307179586 * (double)jm / (double)(NS * 64);
        float c0, s0, c8, s8;
        sincosf((float)(th * (double)x), &s0, &c0);
        sincosf((float)(th * 8.0), &s8, &c8);
        float2 w = make_float2(c0, s0), w8 = make_float2(c8, s8);
#pragma unroll
        for (int u = 0; u < 8; ++u) {
            v[u] = cmul(v[u], w);
            w = cmul(w, w8);
        }
    }
    float2 X[8];
    radix8_inv(v, X);
    {   // inner twiddle e^{+i pi x s2/32}; write exchange
        float cb, sb; sincosf((float)x * 0.09817477042468103f, &sb, &cb);
        float2 wb = make_float2(cb, sb), wc = make_float2(1.f, 0.f);
#pragma unroll
        for (int s2 = 0; s2 < 8; ++s2) {
            ex[gl][x*8 + s2] = cmul(X[s2], wc);
            wc = cmul(wc, wb);
        }
    }
    __syncthreads();
    float2 W2[8];
#pragma unroll
    for (int t1 = 0; t1 < 8; ++t1) W2[t1] = ex[gl][t1*8 + x];
    float2 Y[8];
    radix8_inv(W2, Y);               // output s = x + 8*s1
    if constexpr (NS == 1) {
        __syncthreads();
#pragma unroll
        for (int s1 = 0; s1 < 8; ++s1) ex[gl][x + 8*s1] = Y[s1];
        __syncthreads();
        const long base = (long)blockIdx.x * 2048;
#pragma unroll
        for (int e = 0; e < 8; ++e) {
            int flat = tid*8 + e;
            dst[base + flat] = ex[flat >> 6][flat & 63];
        }
    } else {
        const long obase = (long)(jg - jm) * 64 + jm;
#pragma unroll
        for (int s1 = 0; s1 < 8; ++s1)
            dst[obase + (long)(x + 8*s1) * NS] = Y[s1];
    }
}

// ---------------- radix-8 Stockham inverse FFT pass (final) ----------------
template<int NS>
__global__ __launch_bounds__(256) void ifft_pass8(const float2* __restrict__ src,
                                                  float2* __restrict__ dst) {
    int j = blockIdx.x*256 + threadIdx.x;   // j < NQ
    float2 v[8];
#pragma unroll
    for (int t = 0; t < 8; ++t) v[t] = src[j + t*NQ];
    int jm = j & (NS - 1);
    if constexpr (NS > 1) {
        double base = (double)jm / (double)(NS * 8);
#pragma unroll
        for (int t = 1; t < 8; ++t) {
            float ang = (float)(6.283185307179586 * base * (double)t);
            float sn, cs; sincosf(ang, &sn, &cs);
            v[t] = cmul(v[t], make_float2(cs, sn));
        }
    }
    float2 X[8];
    radix8_inv(v, X);
    int idxD = ((j - jm) << 3) + jm;
#pragma unroll
    for (int s = 0; s < 8; ++s) dst[idxD + s*NS] = X[s];
}

// ---------------- transpose fp32 -> bf16 (w[R][C] -> wT[C][R]) ----------------

__global__ __launch_bounds__(256) void transpose_kernel(const float* __restrict__ w,
                                                        bf16_t* __restrict__ wT,
                                                        int R, int C) {
    __shared__ float tile[32][33];
    int tx = threadIdx.x & 31, ty = threadIdx.x >> 5;
    long c0 = (long)blockIdx.x * 32, r0 = (long)blockIdx.y * 32;
#pragma unroll
    for (int i = 0; i < 4; ++i)
        tile[ty + i*8][tx] = w[(r0 + ty + i*8) * C + c0 + tx];
    __syncthreads();
#pragma unroll
    for (int i = 0; i < 4; ++i) {
        int c = ty + i*8;
        wT[(c0 + c) * R + r0 + tx] = (bf16_t)tile[tx][c];
    }
}

// ---------------- fp32 -> bf16 convert (x) ----------------

__global__ __launch_bounds__(256) void cvt_bf16_kernel(const float* __restrict__ in,
                                                       bf16_t* __restrict__ out, int n4) {
    int i = blockIdx.x*256 + threadIdx.x;
    if (i < n4) {
        float4 v = ((const float4*)in)[i];
        bf4 o;
        o[0] = (bf16_t)v.x; o[1] = (bf16_t)v.y; o[2] = (bf16_t)v.z; o[3] = (bf16_t)v.w;
        ((bf4*)out)[i] = o;
    }
}

// ---------------- 128-tile MFMA GEMM, 8-wave, XOR-swizzled LDS ----------------
// Round-8: both GEMMs on the 8-wave structure (512 thr, 2Mx4N waves, per-wave
// 64x32 out, acc 4x2). Measured on GEMM2 in r7: ~916 TF vs 4-wave's 577.
// LDS[row][cb] = G[row][cb ^ ((row&7)<<4)] (16B granules): pre-swizzled global
// source -> linear global_load_lds dest; reads apply the same XOR (0 conflicts).

__device__ __forceinline__ void stage_tile_sw8(const bf16_t* g, int ld, int row0, int col0,
                                               bf16_t* lds, int tid) {
    int w = tid >> 6, l = tid & 63;        // w in [0,8)
    int r8 = l >> 3;
    int cg = ((l & 7) ^ r8) << 3;
#pragma unroll
    for (int i = 0; i < 2; ++i) {
        int chunk = (i << 3) + w;          // 16 chunks x 8 rows x 64 cols
        const bf16_t* ga = g + (long)(row0 + chunk*8 + r8) * ld + col0 + cg;
        bf16_t* la = lds + (chunk << 9);
        __builtin_amdgcn_global_load_lds((const GLOBAL_AS unsigned int*)ga,
                                         (LDS_AS unsigned int*)la, 16, 0, 0);
    }
}

template<int EPI>  // 0: bias+gelu -> bf16 ; 1: bias -> fp32
__global__ __launch_bounds__(512, 4) void gemm_bt8(const bf16_t* __restrict__ A,
                                                   const bf16_t* __restrict__ Bt,
                                                   const float* __restrict__ bias,
                                                   void* __restrict__ Cout,
                                                   int M, int N, int K) {
    __shared__ __align__(16) bf16_t lA[128*64];
    __shared__ __align__(16) bf16_t lB[128*64];
    const int tid = threadIdx.x;
    const int l = tid & 63, w = tid >> 6;
    const int wr = w >> 2, wc = w & 3;
    const int row0 = blockIdx.y * 128, col0 = blockIdx.x * 128;
    const int lr = l & 15, lq = l >> 4;
    const int xr = (lr & 7) << 4;
    f32x4 acc[4][2] = {};
    for (int k0 = 0; k0 < K; k0 += 64) {
        stage_tile_sw8(A,  K, row0, k0, lA, tid);
        stage_tile_sw8(Bt, K, col0, k0, lB, tid);
        __syncthreads();
#pragma unroll
        for (int kk = 0; kk < 2; ++kk) {
            bf8 af[4], bfr[2];
            const int kb = ((kk << 6) + lq*16) ^ xr;
#pragma unroll
            for (int mi = 0; mi < 4; ++mi)
                af[mi] = *(const bf8*)((const char*)lA + (wr*64 + mi*16 + lr)*128 + kb);
#pragma unroll
            for (int ni = 0; ni < 2; ++ni)
                bfr[ni] = *(const bf8*)((const char*)lB + (wc*32 + ni*16 + lr)*128 + kb);
#pragma unroll
            for (int mi = 0; mi < 4; ++mi)
#pragma unroll
                for (int ni = 0; ni < 2; ++ni)
                    acc[mi][ni] = __builtin_amdgcn_mfma_f32_16x16x32_bf16(
                        af[mi], bfr[ni], acc[mi][ni], 0, 0, 0);
        }
        __syncthreads();
    }
#pragma unroll
    for (int mi = 0; mi < 4; ++mi) {
#pragma unroll
        for (int ni = 0; ni < 2; ++ni) {
            int c = col0 + wc*32 + ni*16 + lr;
            float bv = bias[c];
#pragma unroll
            for (int q = 0; q < 4; ++q) {
                int r = row0 + wr*64 + mi*16 + lq*4 + q;
                float v = acc[mi][ni][q] + bv;
                if constexpr (EPI == 0) {
                    v = 0.5f * v * (1.0f + erff(v * 0.70710678118654752f));
                    ((bf16_t*)Cout)[(long)r * N + c] = (bf16_t)v;
                } else {
                    ((float*)Cout)[(long)r * N + c] = v;
                }
            }
        }
    }
}

// ---------------- launch ----------------

extern "C" void kernel_launch(void* const* d_in, const int* in_sizes, int n_in,
                              void* d_out, int out_size, void* d_ws, size_t ws_size,
                              hipStream_t stream) {
    const float* x        = (const float*)d_in[0];
    const float* fc_cr    = (const float*)d_in[1];
    const float* fc_ci    = (const float*)d_in[2];
    const int*   fc_idx   = (const int*)  d_in[3];
    const float* fc_scale = (const float*)d_in[4];
    const float* fc_bias  = (const float*)d_in[5];
    const float* pj_cr    = (const float*)d_in[6];
    const float* pj_ci    = (const float*)d_in[7];
    const int*   pj_idx   = (const int*)  d_in[8];
    const float* pj_scale = (const float*)d_in[9];
    const float* pj_bias  = (const float*)d_in[10];
    const int keep = in_sizes[1];

    char* ws = (char*)d_ws;
    bf16_t* w_fcT = (bf16_t*)(ws + 0);          //  8 MiB  [4096][1024]
    bf16_t* w_pjT = (bf16_t*)(ws + 8388608);    //  8 MiB  [1024][4096]
    bf16_t* x_bf  = (bf16_t*)(ws + 16777216);   // 16 MiB  [8192][1024]
    bf16_t* h_bf  = (bf16_t*)(ws + 33554432);   // 64 MiB  [8192][4096]
    float2* spec  = (float2*)(ws + 33554432);   // FFT scratch aliases h region
    float2* fftA  = (float2*)(ws + 50331904);
    float2* fftB  = (float2*)(ws + 67109120);

    auto run_decompress = [&](const float* cr, const float* ci, const int* idx,
                              const float* scale, bf16_t* wT, int R, int C) {
        zero2_kernel<<<(M_HALF + 1 + 255)/256, 256, 0, stream>>>(spec, M_HALF + 1);
        scatter_kernel<<<(keep + 255)/256, 256, 0, stream>>>(cr, ci, idx, spec, keep);
        // radices: 64 (prep fused), 64, 64, 8  -> 2^21
        ifft_pass64<1, true>    <<<M64/32, 256, 0, stream>>>(fftA, fftA, spec, scale);
        ifft_pass64<64, false>  <<<M64/32, 256, 0, stream>>>(fftA, fftB, nullptr, nullptr);
        ifft_pass64<4096, false><<<M64/32, 256, 0, stream>>>(fftB, fftA, nullptr, nullptr);
        ifft_pass8<262144>      <<<NQ/256, 256, 0, stream>>>(fftA, fftB);
        dim3 tg(C/32, R/32);
        transpose_kernel<<<tg, 256, 0, stream>>>((const float*)fftB, wT, R, C);
    };

    run_decompress(fc_cr, fc_ci, fc_idx, fc_scale, w_fcT, 1024, 4096);
    run_decompress(pj_cr, pj_ci, pj_idx, pj_scale, w_pjT, 4096, 1024);

    cvt_bf16_kernel<<<8388608/4/256, 256, 0, stream>>>(x, x_bf, 8388608/4);

    // GEMM1: 8-wave 128^2 tiles, grid = 32 x 64 = 2048
    gemm_bt8<0><<<dim3(4096/128, 8192/128), 512, 0, stream>>>(
        x_bf, w_fcT, fc_bias, h_bf, 8192, 4096, 1024);

    // GEMM2: 8-wave 128^2 tiles, grid = 8 x 64 = 512
    gemm_bt8<1><<<dim3(1024/128, 8192/128), 512, 0, stream>>>(
        h_bf, w_pjT, pj_bias, d_out, 8192, 1024, 4096);

    (void)n_in; (void)out_size; (void)ws_size;
}

// Round 9
// 269.123 us; speedup vs baseline: 1.5846x; 1.0084x over previous
//
#include <hip/hip_runtime.h>
#include <hip/hip_bf16.h>
#include <math.h>

#define M_HALF 2097152          // 2^21, half-length complex IFFT size
#define NQ     262144           // M_HALF / 8, threads per radix-8 pass
#define M64    32768            // M_HALF / 64

typedef __bf16 bf16_t;
typedef __attribute__((ext_vector_type(8))) __bf16 bf8;
typedef __attribute__((ext_vector_type(4))) __bf16 bf4;
typedef __attribute__((ext_vector_type(4))) float f32x4;

#define GLOBAL_AS __attribute__((address_space(1)))
#define LDS_AS    __attribute__((address_space(3)))

__device__ __forceinline__ float2 cadd(float2 a, float2 b){ return make_float2(a.x+b.x, a.y+b.y); }
__device__ __forceinline__ float2 csub(float2 a, float2 b){ return make_float2(a.x-b.x, a.y-b.y); }
__device__ __forceinline__ float2 cmul(float2 a, float2 b){ return make_float2(a.x*b.x-a.y*b.y, a.x*b.y+a.y*b.x); }
__device__ __forceinline__ float2 cmuli(float2 a){ return make_float2(-a.y, a.x); } // *(+i)

// inverse 8-point DFT (positive exponent), natural order
__device__ __forceinline__ void radix8_inv(const float2 v[8], float2 X[8]) {
    const float cc = 0.70710678118654752f;
    float2 a0 = cadd(v[0], v[4]), a1 = cadd(v[1], v[5]), a2 = cadd(v[2], v[6]), a3 = cadd(v[3], v[7]);
    float2 b0 = csub(v[0], v[4]), b1 = csub(v[1], v[5]), b2 = csub(v[2], v[6]), b3 = csub(v[3], v[7]);
    b1 = cmul(b1, make_float2(cc, cc));
    b2 = cmuli(b2);
    b3 = cmul(b3, make_float2(-cc, cc));
    float2 c0 = cadd(a0, a2), c1 = cadd(a1, a3), d0 = csub(a0, a2), d1 = cmuli(csub(a1, a3));
    float2 e0 = cadd(b0, b2), e1 = cadd(b1, b3), f0 = csub(b0, b2), f1 = cmuli(csub(b1, b3));
    X[0] = cadd(c0, c1); X[4] = csub(c0, c1); X[2] = cadd(d0, d1); X[6] = csub(d0, d1);
    X[1] = cadd(e0, e1); X[5] = csub(e0, e1); X[3] = cadd(f0, f1); X[7] = csub(f0, f1);
}

// ---------------- zero / scatter ----------------

__global__ __launch_bounds__(256) void zero2_kernel(float2* p, int n) {
    int i = blockIdx.x*256 + threadIdx.x;
    if (i < n) p[i] = make_float2(0.f, 0.f);
}

__global__ __launch_bounds__(256) void scatter_kernel(const float* __restrict__ cr,
                                                      const float* __restrict__ ci,
                                                      const int* __restrict__ idx,
                                                      float2* __restrict__ spec, int keep) {
    int i = blockIdx.x*256 + threadIdx.x;
    if (i < keep) {
        int k = idx[i];
        spec[k] = make_float2(cr[i], ci[i]);
    }
}

// ---------------- radix-64 Stockham inverse FFT pass (two radix-8 + LDS) ----
template<int NS, bool FIRST>
__global__ __launch_bounds__(256) void ifft_pass64(const float2* __restrict__ src,
                                                   float2* __restrict__ dst,
                                                   const float2* __restrict__ spec,
                                                   const float* __restrict__ scale) {
    __shared__ float2 ex[32][65];
    const int tid = threadIdx.x;
    const int x = tid >> 5, gl = tid & 31;
    const int jg = blockIdx.x * 32 + gl;
    const int jm = jg & (NS - 1);
    float2 v[8];
    if constexpr (FIRST) {
        float s = scale[0] * (1.0f/(float)M_HALF);
#pragma unroll
        for (int u = 0; u < 8; ++u) {
            int k = jg + (x + 8*u) * M64;
            float2 a = spec[k];
            float2 b = spec[M_HALF - k];
            if (k == 0) { a.y = 0.0f; b.y = 0.0f; }
            float Er = 0.5f*(a.x + b.x), Ei = 0.5f*(a.y - b.y);
            float Tr = 0.5f*(a.x - b.x), Ti = 0.5f*(a.y + b.y);
            float ang = (float)(3.14159265358979323846 * (double)k / (double)M_HALF);
            float sn, cs; sincosf(ang, &sn, &cs);
            float Or = Tr*cs - Ti*sn, Oi = Tr*sn + Ti*cs;
            v[u] = make_float2((Er - Oi)*s, (Ei + Or)*s);
        }
    } else {
#pragma unroll
        for (int u = 0; u < 8; ++u)
            v[u] = src[jg + (x + 8*u) * M64];
        double th = 6.283185307179586 * (double)jm / (double)(NS * 64);
        float c0, s0, c8, s8;
        sincosf((float)(th * (double)x), &s0, &c0);
        sincosf((float)(th * 8.0), &s8, &c8);
        float2 w = make_float2(c0, s0), w8 = make_float2(c8, s8);
#pragma unroll
        for (int u = 0; u < 8; ++u) {
            v[u] = cmul(v[u], w);
            w = cmul(w, w8);
        }
    }
    float2 X[8];
    radix8_inv(v, X);
    {   // inner twiddle e^{+i pi x s2/32}; write exchange
        float cb, sb; sincosf((float)x * 0.09817477042468103f, &sb, &cb);
        float2 wb = make_float2(cb, sb), wc = make_float2(1.f, 0.f);
#pragma unroll
        for (int s2 = 0; s2 < 8; ++s2) {
            ex[gl][x*8 + s2] = cmul(X[s2], wc);
            wc = cmul(wc, wb);
        }
    }
    __syncthreads();
    float2 W2[8];
#pragma unroll
    for (int t1 = 0; t1 < 8; ++t1) W2[t1] = ex[gl][t1*8 + x];
    float2 Y[8];
    radix8_inv(W2, Y);               // output s = x + 8*s1
    if constexpr (NS == 1) {
        __syncthreads();
#pragma unroll
        for (int s1 = 0; s1 < 8; ++s1) ex[gl][x + 8*s1] = Y[s1];
        __syncthreads();
        const long base = (long)blockIdx.x * 2048;
#pragma unroll
        for (int e = 0; e < 8; ++e) {
            int flat = tid*8 + e;
            dst[base + flat] = ex[flat >> 6][flat & 63];
        }
    } else {
        const long obase = (long)(jg - jm) * 64 + jm;
#pragma unroll
        for (int s1 = 0; s1 < 8; ++s1)
            dst[obase + (long)(x + 8*s1) * NS] = Y[s1];
    }
}

// ---------------- final radix-8 pass, fused bf16 output ----------------
// NS == NQ here, so jm == j and writes dst[j + s*NS] are coalesced across j.
// Half-size-complex unpack: w[2n] = Re z[n], w[2n+1] = Im z[n] -> one packed
// bf16x2 (4B) store per complex output.
template<int NS>
__global__ __launch_bounds__(256) void ifft_pass8_bf(const float2* __restrict__ src,
                                                     bf16_t* __restrict__ dstw) {
    int j = blockIdx.x*256 + threadIdx.x;   // j < NQ
    float2 v[8];
#pragma unroll
    for (int t = 0; t < 8; ++t) v[t] = src[j + t*NQ];
    int jm = j & (NS - 1);
    double base = (double)jm / (double)(NS * 8);
#pragma unroll
    for (int t = 1; t < 8; ++t) {
        float ang = (float)(6.283185307179586 * base * (double)t);
        float sn, cs; sincosf(ang, &sn, &cs);
        v[t] = cmul(v[t], make_float2(cs, sn));
    }
    float2 X[8];
    radix8_inv(v, X);
    int idxD = ((j - jm) << 3) + jm;
#pragma unroll
    for (int s = 0; s < 8; ++s) {
        long n = idxD + (long)s*NS;
        bf16_t lo = (bf16_t)X[s].x, hi = (bf16_t)X[s].y;
        unsigned int pk = ((unsigned int)*(unsigned short*)&hi << 16) |
                           (unsigned int)*(unsigned short*)&lo;
        ((unsigned int*)dstw)[n] = pk;
    }
}

// ---------------- transpose bf16 (w[R][C] -> wT[C][R]) ----------------

__global__ __launch_bounds__(256) void transpose_bf_kernel(const bf16_t* __restrict__ w,
                                                           bf16_t* __restrict__ wT,
                                                           int R, int C) {
    __shared__ bf16_t tile[32][33];
    int tx = threadIdx.x & 31, ty = threadIdx.x >> 5;
    long c0 = (long)blockIdx.x * 32, r0 = (long)blockIdx.y * 32;
#pragma unroll
    for (int i = 0; i < 4; ++i)
        tile[ty + i*8][tx] = w[(r0 + ty + i*8) * C + c0 + tx];
    __syncthreads();
#pragma unroll
    for (int i = 0; i < 4; ++i) {
        int c = ty + i*8;
        wT[(c0 + c) * R + r0 + tx] = tile[tx][c];
    }
}

// ---------------- fp32 -> bf16 convert (x) ----------------

__global__ __launch_bounds__(256) void cvt_bf16_kernel(const float* __restrict__ in,
                                                       bf16_t* __restrict__ out, int n4) {
    int i = blockIdx.x*256 + threadIdx.x;
    if (i < n4) {
        float4 v = ((const float4*)in)[i];
        bf4 o;
        o[0] = (bf16_t)v.x; o[1] = (bf16_t)v.y; o[2] = (bf16_t)v.z; o[3] = (bf16_t)v.w;
        ((bf4*)out)[i] = o;
    }
}

// ---------------- 128-tile MFMA GEMM, 8-wave, XOR-swizzled LDS ----------------
// Round-9: __launch_bounds__(512, 6) -> 3 blocks/CU (24 waves) for GEMM1's
// grid (2048 blocks). Reg budget 512/6 = 85 >= ~70 actually needed, no squeeze.
// GEMM2 (grid 512 = 2/CU) is grid-limited and unaffected -> clean A/B on GEMM1.
// LDS[row][cb] = G[row][cb ^ ((row&7)<<4)] (16B granules): pre-swizzled global
// source -> linear global_load_lds dest; reads apply the same XOR (0 conflicts).

__device__ __forceinline__ void stage_tile_sw8(const bf16_t* g, int ld, int row0, int col0,
                                               bf16_t* lds, int tid) {
    int w = tid >> 6, l = tid & 63;        // w in [0,8)
    int r8 = l >> 3;
    int cg = ((l & 7) ^ r8) << 3;
#pragma unroll
    for (int i = 0; i < 2; ++i) {
        int chunk = (i << 3) + w;          // 16 chunks x 8 rows x 64 cols
        const bf16_t* ga = g + (long)(row0 + chunk*8 + r8) * ld + col0 + cg;
        bf16_t* la = lds + (chunk << 9);
        __builtin_amdgcn_global_load_lds((const GLOBAL_AS unsigned int*)ga,
                                         (LDS_AS unsigned int*)la, 16, 0, 0);
    }
}

template<int EPI>  // 0: bias+gelu -> bf16 ; 1: bias -> fp32
__global__ __launch_bounds__(512, 6) void gemm_bt8(const bf16_t* __restrict__ A,
                                                   const bf16_t* __restrict__ Bt,
                                                   const float* __restrict__ bias,
                                                   void* __restrict__ Cout,
                                                   int M, int N, int K) {
    __shared__ __align__(16) bf16_t lA[128*64];
    __shared__ __align__(16) bf16_t lB[128*64];
    const int tid = threadIdx.x;
    const int l = tid & 63, w = tid >> 6;
    const int wr = w >> 2, wc = w & 3;
    const int row0 = blockIdx.y * 128, col0 = blockIdx.x * 128;
    const int lr = l & 15, lq = l >> 4;
    const int xr = (lr & 7) << 4;
    f32x4 acc[4][2] = {};
    for (int k0 = 0; k0 < K; k0 += 64) {
        stage_tile_sw8(A,  K, row0, k0, lA, tid);
        stage_tile_sw8(Bt, K, col0, k0, lB, tid);
        __syncthreads();
#pragma unroll
        for (int kk = 0; kk < 2; ++kk) {
            bf8 af[4], bfr[2];
            const int kb = ((kk << 6) + lq*16) ^ xr;
#pragma unroll
            for (int mi = 0; mi < 4; ++mi)
                af[mi] = *(const bf8*)((const char*)lA + (wr*64 + mi*16 + lr)*128 + kb);
#pragma unroll
            for (int ni = 0; ni < 2; ++ni)
                bfr[ni] = *(const bf8*)((const char*)lB + (wc*32 + ni*16 + lr)*128 + kb);
#pragma unroll
            for (int mi = 0; mi < 4; ++mi)
#pragma unroll
                for (int ni = 0; ni < 2; ++ni)
                    acc[mi][ni] = __builtin_amdgcn_mfma_f32_16x16x32_bf16(
                        af[mi], bfr[ni], acc[mi][ni], 0, 0, 0);
        }
        __syncthreads();
    }
#pragma unroll
    for (int mi = 0; mi < 4; ++mi) {
#pragma unroll
        for (int ni = 0; ni < 2; ++ni) {
            int c = col0 + wc*32 + ni*16 + lr;
            float bv = bias[c];
#pragma unroll
            for (int q = 0; q < 4; ++q) {
                int r = row0 + wr*64 + mi*16 + lq*4 + q;
                float v = acc[mi][ni][q] + bv;
                if constexpr (EPI == 0) {
                    v = 0.5f * v * (1.0f + erff(v * 0.70710678118654752f));
                    ((bf16_t*)Cout)[(long)r * N + c] = (bf16_t)v;
                } else {
                    ((float*)Cout)[(long)r * N + c] = v;
                }
            }
        }
    }
}

// ---------------- launch ----------------

extern "C" void kernel_launch(void* const* d_in, const int* in_sizes, int n_in,
                              void* d_out, int out_size, void* d_ws, size_t ws_size,
                              hipStream_t stream) {
    const float* x        = (const float*)d_in[0];
    const float* fc_cr    = (const float*)d_in[1];
    const float* fc_ci    = (const float*)d_in[2];
    const int*   fc_idx   = (const int*)  d_in[3];
    const float* fc_scale = (const float*)d_in[4];
    const float* fc_bias  = (const float*)d_in[5];
    const float* pj_cr    = (const float*)d_in[6];
    const float* pj_ci    = (const float*)d_in[7];
    const int*   pj_idx   = (const int*)  d_in[8];
    const float* pj_scale = (const float*)d_in[9];
    const float* pj_bias  = (const float*)d_in[10];
    const int keep = in_sizes[1];

    char* ws = (char*)d_ws;
    bf16_t* w_fcT = (bf16_t*)(ws + 0);          //  8 MiB  [4096][1024]
    bf16_t* w_pjT = (bf16_t*)(ws + 8388608);    //  8 MiB  [1024][4096]
    bf16_t* x_bf  = (bf16_t*)(ws + 16777216);   // 16 MiB  [8192][1024]
    bf16_t* h_bf  = (bf16_t*)(ws + 33554432);   // 64 MiB  [8192][4096]
    float2* spec  = (float2*)(ws + 33554432);   // FFT scratch aliases h region
    float2* fftA  = (float2*)(ws + 50331904);
    float2* fftB  = (float2*)(ws + 67109120);
    bf16_t* w_nat = (bf16_t*)(ws + 67109120);   // bf16 natural-order w (8 MiB)

    auto run_decompress = [&](const float* cr, const float* ci, const int* idx,
                              const float* scale, bf16_t* wT, int R, int C) {
        zero2_kernel<<<(M_HALF + 1 + 255)/256, 256, 0, stream>>>(spec, M_HALF + 1);
        scatter_kernel<<<(keep + 255)/256, 256, 0, stream>>>(cr, ci, idx, spec, keep);
        // radices: 64 (prep fused), 64, 64, 8 (bf16 out)  -> 2^21
        ifft_pass64<1, true>    <<<M64/32, 256, 0, stream>>>(fftA, fftA, spec, scale);
        ifft_pass64<64, false>  <<<M64/32, 256, 0, stream>>>(fftA, fftB, nullptr, nullptr);
        ifft_pass64<4096, false><<<M64/32, 256, 0, stream>>>(fftB, fftA, nullptr, nullptr);
        ifft_pass8_bf<262144>   <<<NQ/256, 256, 0, stream>>>(fftA, w_nat);
        dim3 tg(C/32, R/32);
        transpose_bf_kernel<<<tg, 256, 0, stream>>>(w_nat, wT, R, C);
    };

    run_decompress(fc_cr, fc_ci, fc_idx, fc_scale, w_fcT, 1024, 4096);
    run_decompress(pj_cr, pj_ci, pj_idx, pj_scale, w_pjT, 4096, 1024);

    cvt_bf16_kernel<<<8388608/4/256, 256, 0, stream>>>(x, x_bf, 8388608/4);

    // GEMM1: 8-wave 128^2 tiles, grid = 32 x 64 = 2048
    gemm_bt8<0><<<dim3(4096/128, 8192/128), 512, 0, stream>>>(
        x_bf, w_fcT, fc_bias, h_bf, 8192, 4096, 1024);

    // GEMM2: 8-wave 128^2 tiles, grid = 8 x 64 = 512
    gemm_bt8<1><<<dim3(1024/128, 8192/128), 512, 0, stream>>>(
        h_bf, w_pjT, pj_bias, d_out, 8192, 1024, 4096);

    (void)n_in; (void)out_size; (void)ws_size;
}

// Round 10
// 257.200 us; speedup vs baseline: 1.6580x; 1.0464x over previous
//
#include <hip/hip_runtime.h>
#include <hip/hip_bf16.h>
#include <math.h>

#define M_HALF 2097152          // 2^21, half-length complex IFFT size
#define M64    32768            // M_HALF / 64

typedef __bf16 bf16_t;
typedef __attribute__((ext_vector_type(8))) __bf16 bf8;
typedef __attribute__((ext_vector_type(4))) __bf16 bf4;
typedef __attribute__((ext_vector_type(4))) float f32x4;

#define GLOBAL_AS __attribute__((address_space(1)))
#define LDS_AS    __attribute__((address_space(3)))

__device__ __forceinline__ float2 cadd(float2 a, float2 b){ return make_float2(a.x+b.x, a.y+b.y); }
__device__ __forceinline__ float2 csub(float2 a, float2 b){ return make_float2(a.x-b.x, a.y-b.y); }
__device__ __forceinline__ float2 cmul(float2 a, float2 b){ return make_float2(a.x*b.x-a.y*b.y, a.x*b.y+a.y*b.x); }
__device__ __forceinline__ float2 cmuli(float2 a){ return make_float2(-a.y, a.x); } // *(+i)

// inverse 8-point DFT (positive exponent), natural order
__device__ __forceinline__ void radix8_inv(const float2 v[8], float2 X[8]) {
    const float cc = 0.70710678118654752f;
    float2 a0 = cadd(v[0], v[4]), a1 = cadd(v[1], v[5]), a2 = cadd(v[2], v[6]), a3 = cadd(v[3], v[7]);
    float2 b0 = csub(v[0], v[4]), b1 = csub(v[1], v[5]), b2 = csub(v[2], v[6]), b3 = csub(v[3], v[7]);
    b1 = cmul(b1, make_float2(cc, cc));
    b2 = cmuli(b2);
    b3 = cmul(b3, make_float2(-cc, cc));
    float2 c0 = cadd(a0, a2), c1 = cadd(a1, a3), d0 = csub(a0, a2), d1 = cmuli(csub(a1, a3));
    float2 e0 = cadd(b0, b2), e1 = cadd(b1, b3), f0 = csub(b0, b2), f1 = cmuli(csub(b1, b3));
    X[0] = cadd(c0, c1); X[4] = csub(c0, c1); X[2] = cadd(d0, d1); X[6] = csub(d0, d1);
    X[1] = cadd(e0, e1); X[5] = csub(e0, e1); X[3] = cadd(f0, f1); X[7] = csub(f0, f1);
}

// ---------------- zero / scatter ----------------

__global__ __launch_bounds__(256) void zero2_kernel(float2* p, int n) {
    int i = blockIdx.x*256 + threadIdx.x;
    if (i < n) p[i] = make_float2(0.f, 0.f);
}

__global__ __launch_bounds__(256) void scatter_kernel(const float* __restrict__ cr,
                                                      const float* __restrict__ ci,
                                                      const int* __restrict__ idx,
                                                      float2* __restrict__ spec, int keep) {
    int i = blockIdx.x*256 + threadIdx.x;
    if (i < keep) {
        int k = idx[i];
        spec[k] = make_float2(cr[i], ci[i]);
    }
}

// ---------------- first pass: radix-512 in-block (8^3), prep fused, NS=1 ----
// Per j in [0,4096): d[t] = prep(spec, k=j+t*4096), t in [0,512);
// D[s] = sum_t d[t] e^{+2pi i st/512}; out dst[j*512 + s] (natural order).
// Block: 512 thr = 8 j (jl=tid&7) x 64 x (x=tid>>3). Three radix-8 stages:
//   E = R8(v over u);  F[s8] = E[s8]*cis(2pi s8 x/512)     -> L1[s8*65+x]
//   g[xb]=L1[p*65+xa+8xb], p=x>>3,xa=x&7; H = R8(g);
//   Hp[o8] = H[o8]*cis(2pi o8 xa/64)                       -> L2[p*81+o8*9+xa]
//   r[xa]=L2[pp*81+sp*9+xa], pp=x&7,sp=x>>3; D = R8(r)     -> s = x + 64*ob
__global__ __launch_bounds__(512) void ifft_pass512_first(const float2* __restrict__ spec,
                                                          float2* __restrict__ dst,
                                                          const float* __restrict__ scale) {
    __shared__ float2 ex[8 * 642];
    const int tid = threadIdx.x;
    const int jl = tid & 7, x = tid >> 3;
    const int j = blockIdx.x * 8 + jl;
    float2* W = ex + jl * 642;

    float2 v[8];
    const float s = scale[0] * (1.0f/(float)M_HALF);
#pragma unroll
    for (int u = 0; u < 8; ++u) {
        int k = j + (x + 64*u) * 4096;
        float2 a = spec[k];
        float2 b = spec[M_HALF - k];
        if (k == 0) { a.y = 0.0f; b.y = 0.0f; }
        float Er = 0.5f*(a.x + b.x), Ei = 0.5f*(a.y - b.y);
        float Tr = 0.5f*(a.x - b.x), Ti = 0.5f*(a.y + b.y);
        float ang = (float)(3.14159265358979323846 * (double)k / (double)M_HALF);
        float sn, cs; sincosf(ang, &sn, &cs);
        float Or = Tr*cs - Ti*sn, Oi = Tr*sn + Ti*cs;
        v[u] = make_float2((Er - Oi)*s, (Ei + Or)*s);
    }
    float2 E[8];
    radix8_inv(v, E);
    {   // T1 = cis(2pi s8 x / 512), recurrence over s8
        float cb, sb; sincosf((float)x * 0.012271846303085130f, &sb, &cb);
        float2 wb = make_float2(cb, sb), w = make_float2(1.f, 0.f);
#pragma unroll
        for (int s8 = 0; s8 < 8; ++s8) {
            W[s8*65 + x] = cmul(E[s8], w);
            w = cmul(w, wb);
        }
    }
    __syncthreads();
    const int p = x >> 3, xa = x & 7;
    float2 g[8];
#pragma unroll
    for (int xb = 0; xb < 8; ++xb) g[xb] = W[p*65 + xa + 8*xb];
    float2 H[8];
    radix8_inv(g, H);
    __syncthreads();                       // all L1 reads done before L2 writes
    {   // T2 = cis(2pi o8 xa / 64), recurrence over o8
        float cb, sb; sincosf((float)xa * 0.098174770424681039f, &sb, &cb);
        float2 wb = make_float2(cb, sb), w = make_float2(1.f, 0.f);
#pragma unroll
        for (int o8 = 0; o8 < 8; ++o8) {
            W[p*81 + o8*9 + xa] = cmul(H[o8], w);
            w = cmul(w, wb);
        }
    }
    __syncthreads();
    const int pp = x & 7, sp = x >> 3;
    float2 r[8];
#pragma unroll
    for (int xa2 = 0; xa2 < 8; ++xa2) r[xa2] = W[pp*81 + sp*9 + xa2];
    float2 D[8];
    radix8_inv(r, D);                      // D[ob] -> s = x + 64*ob
    // coalesced store: lane x writes s = x + 64*ob, base j*512 (512B wave-runs)
    const long base = (long)j * 512;
#pragma unroll
    for (int ob = 0; ob < 8; ++ob)
        dst[base + x + 64*ob] = D[ob];
}

// ---------------- radix-64 Stockham middle pass (two radix-8 + LDS) ----------
template<int NS>
__global__ __launch_bounds__(256) void ifft_pass64(const float2* __restrict__ src,
                                                   float2* __restrict__ dst) {
    __shared__ float2 ex[32][65];
    const int tid = threadIdx.x;
    const int x = tid >> 5, gl = tid & 31;
    const int jg = blockIdx.x * 32 + gl;
    const int jm = jg & (NS - 1);
    float2 v[8];
#pragma unroll
    for (int u = 0; u < 8; ++u)
        v[u] = src[jg + (x + 8*u) * M64];
    {
        double th = 6.283185307179586 * (double)jm / (double)(NS * 64);
        float c0, s0, c8, s8;
        sincosf((float)(th * (double)x), &s0, &c0);
        sincosf((float)(th * 8.0), &s8, &c8);
        float2 w = make_float2(c0, s0), w8 = make_float2(c8, s8);
#pragma unroll
        for (int u = 0; u < 8; ++u) {
            v[u] = cmul(v[u], w);
            w = cmul(w, w8);
        }
    }
    float2 X[8];
    radix8_inv(v, X);
    {   // inner twiddle e^{+i pi x s2/32}
        float cb, sb; sincosf((float)x * 0.09817477042468103f, &sb, &cb);
        float2 wb = make_float2(cb, sb), wc = make_float2(1.f, 0.f);
#pragma unroll
        for (int s2 = 0; s2 < 8; ++s2) {
            ex[gl][x*8 + s2] = cmul(X[s2], wc);
            wc = cmul(wc, wb);
        }
    }
    __syncthreads();
    float2 W2[8];
#pragma unroll
    for (int t1 = 0; t1 < 8; ++t1) W2[t1] = ex[gl][t1*8 + x];
    float2 Y[8];
    radix8_inv(W2, Y);
    const long obase = (long)(jg - jm) * 64 + jm;
#pragma unroll
    for (int s1 = 0; s1 < 8; ++s1)
        dst[obase + (long)(x + 8*s1) * NS] = Y[s1];
}

// ---------------- radix-64 FINAL pass, packed-bf16 output ----------------
// NS = 32768 here: jm = jg, obase = jg; writes u32(bf16 Re,Im) at n = jg + s*NS
// (32 consecutive jg per block -> 128B coalesced runs per s-stream).
template<int NS>
__global__ __launch_bounds__(256) void ifft_pass64_bf(const float2* __restrict__ src,
                                                      bf16_t* __restrict__ dstw) {
    __shared__ float2 ex[32][65];
    const int tid = threadIdx.x;
    const int x = tid >> 5, gl = tid & 31;
    const int jg = blockIdx.x * 32 + gl;
    const int jm = jg & (NS - 1);
    float2 v[8];
#pragma unroll
    for (int u = 0; u < 8; ++u)
        v[u] = src[jg + (x + 8*u) * M64];
    {
        double th = 6.283185307179586 * (double)jm / (double)(NS * 64);
        float c0, s0, c8, s8;
        sincosf((float)(th * (double)x), &s0, &c0);
        sincosf((float)(th * 8.0), &s8, &c8);
        float2 w = make_float2(c0, s0), w8 = make_float2(c8, s8);
#pragma unroll
        for (int u = 0; u < 8; ++u) {
            v[u] = cmul(v[u], w);
            w = cmul(w, w8);
        }
    }
    float2 X[8];
    radix8_inv(v, X);
    {
        float cb, sb; sincosf((float)x * 0.09817477042468103f, &sb, &cb);
        float2 wb = make_float2(cb, sb), wc = make_float2(1.f, 0.f);
#pragma unroll
        for (int s2 = 0; s2 < 8; ++s2) {
            ex[gl][x*8 + s2] = cmul(X[s2], wc);
            wc = cmul(wc, wb);
        }
    }
    __syncthreads();
    float2 W2[8];
#pragma unroll
    for (int t1 = 0; t1 < 8; ++t1) W2[t1] = ex[gl][t1*8 + x];
    float2 Y[8];
    radix8_inv(W2, Y);
    const long obase = (long)(jg - jm) * 64 + jm;
#pragma unroll
    for (int s1 = 0; s1 < 8; ++s1) {
        long n = obase + (long)(x + 8*s1) * NS;
        bf16_t lo = (bf16_t)Y[s1].x, hi = (bf16_t)Y[s1].y;
        unsigned int pk = ((unsigned int)*(unsigned short*)&hi << 16) |
                           (unsigned int)*(unsigned short*)&lo;
        ((unsigned int*)dstw)[n] = pk;
    }
}

// ---------------- transpose bf16 (w[R][C] -> wT[C][R]) ----------------

__global__ __launch_bounds__(256) void transpose_bf_kernel(const bf16_t* __restrict__ w,
                                                           bf16_t* __restrict__ wT,
                                                           int R, int C) {
    __shared__ bf16_t tile[32][33];
    int tx = threadIdx.x & 31, ty = threadIdx.x >> 5;
    long c0 = (long)blockIdx.x * 32, r0 = (long)blockIdx.y * 32;
#pragma unroll
    for (int i = 0; i < 4; ++i)
        tile[ty + i*8][tx] = w[(r0 + ty + i*8) * C + c0 + tx];
    __syncthreads();
#pragma unroll
    for (int i = 0; i < 4; ++i) {
        int c = ty + i*8;
        wT[(c0 + c) * R + r0 + tx] = tile[tx][c];
    }
}

// ---------------- fp32 -> bf16 convert (x) ----------------

__global__ __launch_bounds__(256) void cvt_bf16_kernel(const float* __restrict__ in,
                                                       bf16_t* __restrict__ out, int n4) {
    int i = blockIdx.x*256 + threadIdx.x;
    if (i < n4) {
        float4 v = ((const float4*)in)[i];
        bf4 o;
        o[0] = (bf16_t)v.x; o[1] = (bf16_t)v.y; o[2] = (bf16_t)v.z; o[3] = (bf16_t)v.w;
        ((bf4*)out)[i] = o;
    }
}

// ---------------- 128-tile MFMA GEMM, 8-wave, XOR-swizzled LDS ----------------
// Round-10: XCD-chunked block swizzle (T1). 8 XCDs get CRxCC-tile chunks so the
// per-XCD working set ~ L2 (GEMM1: 16x16 -> A 4MB + B 4MB). Bijective since
// grid is a multiple of 8 and CR*CC*8 == gx*gy.
// LDS[row][cb] = G[row][cb ^ ((row&7)<<4)] (16B granules): pre-swizzled global
// source -> linear global_load_lds dest; reads apply the same XOR (0 conflicts).

__device__ __forceinline__ void stage_tile_sw8(const bf16_t* g, int ld, int row0, int col0,
                                               bf16_t* lds, int tid) {
    int w = tid >> 6, l = tid & 63;        // w in [0,8)
    int r8 = l >> 3;
    int cg = ((l & 7) ^ r8) << 3;
#pragma unroll
    for (int i = 0; i < 2; ++i) {
        int chunk = (i << 3) + w;          // 16 chunks x 8 rows x 64 cols
        const bf16_t* ga = g + (long)(row0 + chunk*8 + r8) * ld + col0 + cg;
        bf16_t* la = lds + (chunk << 9);
        __builtin_amdgcn_global_load_lds((const GLOBAL_AS unsigned int*)ga,
                                         (LDS_AS unsigned int*)la, 16, 0, 0);
    }
}

template<int EPI>  // 0: bias+gelu -> bf16 ; 1: bias -> fp32
__global__ __launch_bounds__(512, 6) void gemm_bt8(const bf16_t* __restrict__ A,
                                                   const bf16_t* __restrict__ Bt,
                                                   const float* __restrict__ bias,
                                                   void* __restrict__ Cout,
                                                   int M, int N, int K,
                                                   int CR, int CC, int GXC) {
    __shared__ __align__(16) bf16_t lA[128*64];
    __shared__ __align__(16) bf16_t lB[128*64];
    const int tid = threadIdx.x;
    const int l = tid & 63, w = tid >> 6;
    const int wr = w >> 2, wc = w & 3;
    // XCD-chunked swizzle: xcd r covers a CR x CC tile chunk
    int flat = blockIdx.y * gridDim.x + blockIdx.x;
    int r = flat & 7, q = flat >> 3;
    int ty = (r / GXC) * CR + q / CC;
    int tx = (r % GXC) * CC + q % CC;
    const int row0 = ty * 128, col0 = tx * 128;
    const int lr = l & 15, lq = l >> 4;
    const int xr = (lr & 7) << 4;
    f32x4 acc[4][2] = {};
    for (int k0 = 0; k0 < K; k0 += 64) {
        stage_tile_sw8(A,  K, row0, k0, lA, tid);
        stage_tile_sw8(Bt, K, col0, k0, lB, tid);
        __syncthreads();
#pragma unroll
        for (int kk = 0; kk < 2; ++kk) {
            bf8 af[4], bfr[2];
            const int kb = ((kk << 6) + lq*16) ^ xr;
#pragma unroll
            for (int mi = 0; mi < 4; ++mi)
                af[mi] = *(const bf8*)((const char*)lA + (wr*64 + mi*16 + lr)*128 + kb);
#pragma unroll
            for (int ni = 0; ni < 2; ++ni)
                bfr[ni] = *(const bf8*)((const char*)lB + (wc*32 + ni*16 + lr)*128 + kb);
#pragma unroll
            for (int mi = 0; mi < 4; ++mi)
#pragma unroll
                for (int ni = 0; ni < 2; ++ni)
                    acc[mi][ni] = __builtin_amdgcn_mfma_f32_16x16x32_bf16(
                        af[mi], bfr[ni], acc[mi][ni], 0, 0, 0);
        }
        __syncthreads();
    }
#pragma unroll
    for (int mi = 0; mi < 4; ++mi) {
#pragma unroll
        for (int ni = 0; ni < 2; ++ni) {
            int c = col0 + wc*32 + ni*16 + lr;
            float bv = bias[c];
#pragma unroll
            for (int q2 = 0; q2 < 4; ++q2) {
                int rr = row0 + wr*64 + mi*16 + lq*4 + q2;
                float v = acc[mi][ni][q2] + bv;
                if constexpr (EPI == 0) {
                    v = 0.5f * v * (1.0f + erff(v * 0.70710678118654752f));
                    ((bf16_t*)Cout)[(long)rr * N + c] = (bf16_t)v;
                } else {
                    ((float*)Cout)[(long)rr * N + c] = v;
                }
            }
        }
    }
}

// ---------------- launch ----------------

extern "C" void kernel_launch(void* const* d_in, const int* in_sizes, int n_in,
                              void* d_out, int out_size, void* d_ws, size_t ws_size,
                              hipStream_t stream) {
    const float* x        = (const float*)d_in[0];
    const float* fc_cr    = (const float*)d_in[1];
    const float* fc_ci    = (const float*)d_in[2];
    const int*   fc_idx   = (const int*)  d_in[3];
    const float* fc_scale = (const float*)d_in[4];
    const float* fc_bias  = (const float*)d_in[5];
    const float* pj_cr    = (const float*)d_in[6];
    const float* pj_ci    = (const float*)d_in[7];
    const int*   pj_idx   = (const int*)  d_in[8];
    const float* pj_scale = (const float*)d_in[9];
    const float* pj_bias  = (const float*)d_in[10];
    const int keep = in_sizes[1];

    char* ws = (char*)d_ws;
    bf16_t* w_fcT = (bf16_t*)(ws + 0);          //  8 MiB  [4096][1024]
    bf16_t* w_pjT = (bf16_t*)(ws + 8388608);    //  8 MiB  [1024][4096]
    bf16_t* x_bf  = (bf16_t*)(ws + 16777216);   // 16 MiB  [8192][1024]
    bf16_t* h_bf  = (bf16_t*)(ws + 33554432);   // 64 MiB  [8192][4096]
    // FFT scratch nested inside the h_bf window (all FFT work precedes GEMM1):
    float2* spec  = (float2*)(ws + 33554432);   // 32 MiB ..48 MiB+8
    float2* fftA  = (float2*)(ws + 51380224);   // 49 MiB ..65 MiB
    float2* fftB  = (float2*)(ws + 69206016);   // 66 MiB ..82 MiB
    bf16_t* w_nat = (bf16_t*)(ws + 87031808);   // 83 MiB ..91 MiB (bf16 packed)

    auto run_decompress = [&](const float* cr, const float* ci, const int* idx,
                              const float* scale, bf16_t* wT, int R, int C) {
        zero2_kernel<<<(M_HALF + 1 + 255)/256, 256, 0, stream>>>(spec, M_HALF + 1);
        scatter_kernel<<<(keep + 255)/256, 256, 0, stream>>>(cr, ci, idx, spec, keep);
        // radices: 512 (prep fused, in-block 8^3), 64, 64 (bf16 out) -> 2^21
        ifft_pass512_first<<<4096/8, 512, 0, stream>>>(spec, fftA, scale);
        ifft_pass64<512>   <<<M64/32, 256, 0, stream>>>(fftA, fftB);
        ifft_pass64_bf<32768><<<M64/32, 256, 0, stream>>>(fftB, w_nat);
        dim3 tg(C/32, R/32);
        transpose_bf_kernel<<<tg, 256, 0, stream>>>(w_nat, wT, R, C);
    };

    run_decompress(fc_cr, fc_ci, fc_idx, fc_scale, w_fcT, 1024, 4096);
    run_decompress(pj_cr, pj_ci, pj_idx, pj_scale, w_pjT, 4096, 1024);

    cvt_bf16_kernel<<<8388608/4/256, 256, 0, stream>>>(x, x_bf, 8388608/4);

    // GEMM1: grid 32x64 = 2048 tiles; XCD chunks 16x16 (GXC = 32/16 = 2)
    gemm_bt8<0><<<dim3(4096/128, 8192/128), 512, 0, stream>>>(
        x_bf, w_fcT, fc_bias, h_bf, 8192, 4096, 1024, 16, 16, 2);

    // GEMM2: grid 8x64 = 512 tiles; XCD chunks 8x8 (GXC = 8/8 = 1)
    gemm_bt8<1><<<dim3(1024/128, 8192/128), 512, 0, stream>>>(
        h_bf, w_pjT, pj_bias, d_out, 8192, 1024, 4096, 8, 8, 1);

    (void)n_in; (void)out_size; (void)ws_size;
}